// Round 2
// baseline (38736.456 us; speedup 1.0000x reference)
//
#include <hip/hip_runtime.h>
#include <hip/hip_cooperative_groups.h>
#include <hip/hip_bf16.h>
#include <cmath>

namespace cg = cooperative_groups;

// Problem constants
#define BATCH 16
#define SEQ 256
#define EMBED 512
#define HIDDEN 1024
#define GATES 4096       // 4*HIDDEN
#define VOCAB 32000
#define MROWS 4096       // BATCH*SEQ
#define LOGITS_SZ 131072000  // 16*256*32000

#define RBLOCKS 256
#define RTHREADS 512

typedef unsigned int u32;
typedef unsigned short u16;
typedef __attribute__((ext_vector_type(8))) short bf16x8;
typedef __attribute__((ext_vector_type(4))) float f32x4;

#define AS1 __attribute__((address_space(1)))
#define AS3 __attribute__((address_space(3)))

// ---------------- embedding gather ----------------
// X0[(s*16+b)*512 + e] = emb[x[b*256+s]*512 + e]
__global__ void embed_kernel(const int* __restrict__ x, const float* __restrict__ emb,
                             float* __restrict__ X0) {
    int r = blockIdx.x;            // r = s*16 + b
    int s = r >> 4, b = r & 15;
    int tok = x[b * SEQ + s];
    const float4* src = (const float4*)(emb + (size_t)tok * EMBED);
    float4* dst = (float4*)(X0 + (size_t)r * EMBED);
    for (int i = threadIdx.x; i < EMBED / 4; i += blockDim.x) dst[i] = src[i];
}

// ---------------- fp32 GEMM: C[M,N] = A[M,K] @ B[N,K]^T + b1 + b2 ----------------
// 128x128 block tile, BK=8, 256 threads, 8x8 microtile. (layer input projections)
__global__ __launch_bounds__(256) void gemm_bt(
    const float* __restrict__ A, const float* __restrict__ B,
    const float* __restrict__ b1, const float* __restrict__ b2,
    float* __restrict__ C, int M, int N, int K, int perm) {
    __shared__ float As[8][128];
    __shared__ float Bs[8][128];
    int tid = threadIdx.x;
    int bm = blockIdx.y, bn = blockIdx.x;
    int arow = tid >> 1;              // 0..127
    int ak4 = (tid & 1) * 4;          // 0 or 4
    const float* Ag = A + (size_t)(bm * 128 + arow) * K + ak4;
    const float* Bg = B + (size_t)(bn * 128 + arow) * K + ak4;
    int tx = tid & 15, ty = tid >> 4;

    float acc[8][8];
#pragma unroll
    for (int i = 0; i < 8; i++)
#pragma unroll
        for (int j = 0; j < 8; j++) acc[i][j] = 0.f;

    for (int k0 = 0; k0 < K; k0 += 8) {
        float4 a4 = *(const float4*)(Ag + k0);
        float4 b4 = *(const float4*)(Bg + k0);
        __syncthreads();
        As[ak4 + 0][arow] = a4.x; As[ak4 + 1][arow] = a4.y;
        As[ak4 + 2][arow] = a4.z; As[ak4 + 3][arow] = a4.w;
        Bs[ak4 + 0][arow] = b4.x; Bs[ak4 + 1][arow] = b4.y;
        Bs[ak4 + 2][arow] = b4.z; Bs[ak4 + 3][arow] = b4.w;
        __syncthreads();
#pragma unroll
        for (int k = 0; k < 8; k++) {
            float av[8], bv[8];
            *(float4*)(av + 0) = *(const float4*)&As[k][ty * 8 + 0];
            *(float4*)(av + 4) = *(const float4*)&As[k][ty * 8 + 4];
            *(float4*)(bv + 0) = *(const float4*)&Bs[k][tx * 8 + 0];
            *(float4*)(bv + 4) = *(const float4*)&Bs[k][tx * 8 + 4];
#pragma unroll
            for (int i = 0; i < 8; i++)
#pragma unroll
                for (int j = 0; j < 8; j++) acc[i][j] += av[i] * bv[j];
        }
    }

#pragma unroll
    for (int i = 0; i < 8; i++) {
        int r = bm * 128 + ty * 8 + i;
        int orow = perm ? ((r & 15) * SEQ + (r >> 4)) : r;
#pragma unroll
        for (int j = 0; j < 8; j += 4) {
            int c = bn * 128 + tx * 8 + j;
            float4 v;
            float bb0 = (b1 ? b1[c + 0] : 0.f) + (b2 ? b2[c + 0] : 0.f);
            float bb1 = (b1 ? b1[c + 1] : 0.f) + (b2 ? b2[c + 1] : 0.f);
            float bb2 = (b1 ? b1[c + 2] : 0.f) + (b2 ? b2[c + 2] : 0.f);
            float bb3 = (b1 ? b1[c + 3] : 0.f) + (b2 ? b2[c + 3] : 0.f);
            v.x = acc[i][j + 0] + bb0;
            v.y = acc[i][j + 1] + bb1;
            v.z = acc[i][j + 2] + bb2;
            v.w = acc[i][j + 3] + bb3;
            *(float4*)&C[(size_t)orow * N + c] = v;
        }
    }
}

// ---------------- fp32 -> bf16 conversion (RNE), 8 elems/thread ----------------
__device__ __forceinline__ u32 f2bf(float f) {
    u32 u = __float_as_uint(f);
    return (u + 0x7fffu + ((u >> 16) & 1u)) >> 16;
}

__global__ __launch_bounds__(256) void f32_to_bf16_kernel(
    const float* __restrict__ in, u16* __restrict__ out, int n8) {
    for (int i = blockIdx.x * 256 + threadIdx.x; i < n8; i += gridDim.x * 256) {
        float4 a = ((const float4*)in)[2 * (size_t)i + 0];
        float4 b = ((const float4*)in)[2 * (size_t)i + 1];
        uint4 o;
        o.x = f2bf(a.x) | (f2bf(a.y) << 16);
        o.y = f2bf(a.z) | (f2bf(a.w) << 16);
        o.z = f2bf(b.x) | (f2bf(b.y) << 16);
        o.w = f2bf(b.z) | (f2bf(b.w) << 16);
        ((uint4*)out)[i] = o;
    }
}

// ---------------- bf16 MFMA FC GEMM ----------------
// C[perm(r)][c] = sum_k Abf[r][k]*Bbf[c][k] + bias[c]
// 128x128 tile, BK=32, 4 waves (2x2), 4x4 16x16x32 frags per wave.
__global__ __launch_bounds__(256) void fc_mfma(
    const u16* __restrict__ Abf,   // [MROWS][1024] bf16
    const u16* __restrict__ Bbf,   // [VOCAB][1024] bf16
    const float* __restrict__ bias,
    float* __restrict__ C) {
    const int K = HIDDEN;          // 1024
    const int N = VOCAB;
    __shared__ char smem[16384];   // As 8KB + Bs 8KB
    char* As = smem;
    char* Bs = smem + 8192;

    int tid = threadIdx.x;
    int w = tid >> 6, l = tid & 63;
    int bn = blockIdx.x, bm = blockIdx.y;
    int wr = w >> 1, wc = w & 1;
    int lr = l & 15, lk = l >> 4;

    f32x4 acc[4][4];
#pragma unroll
    for (int m = 0; m < 4; m++)
#pragma unroll
        for (int n = 0; n < 4; n++) acc[m][n] = {0.f, 0.f, 0.f, 0.f};

    int srow = tid >> 2, skc = (tid & 3) * 8;
    const u16* ga0 = Abf + (size_t)(bm * 128 + srow) * K + skc;
    const u16* ga1 = Abf + (size_t)(bm * 128 + 64 + srow) * K + skc;
    const u16* gb0 = Bbf + (size_t)(bn * 128 + srow) * K + skc;
    const u16* gb1 = Bbf + (size_t)(bn * 128 + 64 + srow) * K + skc;
    char* la0 = As + w * 1024;
    char* la1 = As + 4096 + w * 1024;
    char* lb0 = Bs + w * 1024;
    char* lb1 = Bs + 4096 + w * 1024;

    int afo[4], bfo[4];
#pragma unroll
    for (int m = 0; m < 4; m++) afo[m] = (wr * 64 + m * 16 + lr) * 64 + lk * 16;
#pragma unroll
    for (int n = 0; n < 4; n++) bfo[n] = (wc * 64 + n * 16 + lr) * 64 + lk * 16;

    for (int k0 = 0; k0 < K; k0 += 32) {
        __syncthreads();
        __builtin_amdgcn_global_load_lds((const AS1 u32*)(const void*)(ga0 + k0),
                                         (AS3 u32*)(void*)la0, 16, 0, 0);
        __builtin_amdgcn_global_load_lds((const AS1 u32*)(const void*)(ga1 + k0),
                                         (AS3 u32*)(void*)la1, 16, 0, 0);
        __builtin_amdgcn_global_load_lds((const AS1 u32*)(const void*)(gb0 + k0),
                                         (AS3 u32*)(void*)lb0, 16, 0, 0);
        __builtin_amdgcn_global_load_lds((const AS1 u32*)(const void*)(gb1 + k0),
                                         (AS3 u32*)(void*)lb1, 16, 0, 0);
        __syncthreads();

        bf16x8 af[4], bfr[4];
#pragma unroll
        for (int m = 0; m < 4; m++) af[m] = *(const bf16x8*)(As + afo[m]);
#pragma unroll
        for (int n = 0; n < 4; n++) bfr[n] = *(const bf16x8*)(Bs + bfo[n]);
#pragma unroll
        for (int m = 0; m < 4; m++)
#pragma unroll
            for (int n = 0; n < 4; n++)
                acc[m][n] = __builtin_amdgcn_mfma_f32_16x16x32_bf16(
                    af[m], bfr[n], acc[m][n], 0, 0, 0);
    }

    int rbase = bm * 128 + wr * 64 + lk * 4;
    int cbase = bn * 128 + wc * 64 + lr;
#pragma unroll
    for (int m = 0; m < 4; m++) {
#pragma unroll
        for (int n = 0; n < 4; n++) {
            int c = cbase + n * 16;
            float bb = bias[c];
#pragma unroll
            for (int j = 0; j < 4; j++) {
                int r = rbase + m * 16 + j;
                int orow = (r & 15) * SEQ + (r >> 4);   // [B,S,V] layout
                C[(size_t)orow * N + c] = acc[m][n][j] + bb;
            }
        }
    }
}

// ---------------- persistent cooperative LSTM layer ----------------
// 256 blocks x 512 threads. Block owns 4 hidden units (16 gate cols) over full K.
// Weights in registers (32/thread), h broadcast via parity-double-buffered global,
// c-state in registers of the 64 update threads. One grid.sync per step.
__global__ __launch_bounds__(RTHREADS) void lstm_layer_persistent(
    const float* __restrict__ Whh,    // [4096][1024] row-major (gate row n, k)
    const float* __restrict__ G,      // [4096][4096] rows t*16+b (x-proj + both biases)
    const float* __restrict__ c_init, // [16][1024] this layer's c0
    float* __restrict__ c_out,        // [16][1024] final c
    float* __restrict__ Hseq,         // [4096][1024] rows t*16+b
    float* __restrict__ hb0,          // [1024][16] parity-0 h (pre-loaded with h0)
    float* __restrict__ hb1) {        // [1024][16] parity-1 h (scratch)
    __shared__ float Hl[1024][16];      // 64 KB: h[k][b]
    __shared__ float Pl[16][16][33];    // 33.8 KB: partials [col][b][kc] (+pad)
    __shared__ float Sl[16][17];        // gate sums [col][b] (+pad)
    cg::grid_group grid = cg::this_grid();

    const int tid = threadIdx.x;
    const int j0 = blockIdx.x * 4;           // 4 hidden units per block
    const int c = tid & 15;                  // col within block: c = g*4 + jj
    const int kc = tid >> 4;                 // 0..31, k-chunk (interleaved, stride 32)
    const int nrow = (c >> 2) * HIDDEN + j0 + (c & 3);

    // W_hh slice into registers: thread owns col c, k = kc + 32*i (i=0..31)
    float w[32];
    {
        const float* wr = Whh + (size_t)nrow * HIDDEN + kc;
#pragma unroll
        for (int i = 0; i < 32; i++) w[i] = wr[i * 32];
    }

    const int ub = tid >> 2, ujj = tid & 3;  // update mapping for tid<64: (batch, jj)
    float creg = 0.f;
    if (tid < 64) creg = c_init[ub * HIDDEN + j0 + ujj];

    for (int t = 0; t < SEQ; t++) {
        // prefetch this step's input-projection gates (hide HBM latency under GEMM)
        float gp0, gp1, gp2, gp3;
        if (tid < 64) {
            const float* gp = G + ((size_t)(t * BATCH + ub)) * GATES + j0 + ujj;
            gp0 = gp[0]; gp1 = gp[HIDDEN]; gp2 = gp[2 * HIDDEN]; gp3 = gp[3 * HIDDEN];
        }
        // stage h_{t} into LDS (written by all blocks last step; grid.sync ordered)
        {
            const float4* src = (const float4*)((t & 1) ? hb1 : hb0);
            float4* dst = (float4*)&Hl[0][0];
#pragma unroll
            for (int i = 0; i < 8; i++) dst[tid * 8 + i] = src[tid * 8 + i];
        }
        __syncthreads();

        // partial recurrent GEMM: acc[b] = sum_{k in chunk} W[c][k] * h[k][b]
        float acc[16];
#pragma unroll
        for (int b = 0; b < 16; b++) acc[b] = 0.f;
#pragma unroll
        for (int i = 0; i < 32; i++) {
            const float wv = w[i];
            const float* hp = &Hl[kc + i * 32][0];
#pragma unroll
            for (int b = 0; b < 16; b++) acc[b] += wv * hp[b];
        }
#pragma unroll
        for (int b = 0; b < 16; b++) Pl[c][b][kc] = acc[b];
        __syncthreads();

        // reduce 32 k-chunk partials per (col, b)
        if (tid < 256) {
            const int c2 = tid & 15, b2 = tid >> 4;
            float s = 0.f;
#pragma unroll
            for (int q = 0; q < 32; q++) s += Pl[c2][b2][q];
            Sl[c2][b2] = s;
        }
        __syncthreads();

        // LSTM pointwise update for this block's 4 hidden units x 16 batches
        if (tid < 64) {
            const float gi_ = gp0 + Sl[ujj][ub];
            const float gf_ = gp1 + Sl[4 + ujj][ub];
            const float gg_ = gp2 + Sl[8 + ujj][ub];
            const float go_ = gp3 + Sl[12 + ujj][ub];
            const float ig = 1.f / (1.f + __expf(-gi_));
            const float fg = 1.f / (1.f + __expf(-gf_));
            const float gt = tanhf(gg_);
            const float og = 1.f / (1.f + __expf(-go_));
            creg = fg * creg + ig * gt;
            const float h = og * tanhf(creg);
            Hseq[((size_t)(t * BATCH + ub)) * HIDDEN + j0 + ujj] = h;
            float* hbn = (t & 1) ? hb0 : hb1;
            hbn[(j0 + ujj) * BATCH + ub] = h;
        }
        __threadfence();
        grid.sync();
    }
    if (tid < 64) c_out[ub * HIDDEN + j0 + ujj] = creg;
}

// ---------------- init & tails ----------------
__global__ void init_state(const float* __restrict__ h0, const float* __restrict__ c0,
                           float* __restrict__ c_ws, float* __restrict__ ht0,
                           float* __restrict__ ht1) {
    int gid = blockIdx.x * 256 + threadIdx.x;  // 32768
    c_ws[gid] = c0[gid];
    int l = gid >> 14, b = (gid >> 10) & 15, j = gid & 1023;
    float h = h0[gid];
    float* htp = l ? ht1 : ht0;
    htp[j * BATCH + b] = h;
}

__global__ void write_tails(const float* __restrict__ Hseq0, const float* __restrict__ Hseq1,
                            const float* __restrict__ c_ws, float* __restrict__ out) {
    int gid = blockIdx.x * 256 + threadIdx.x;  // 32768
    int l = gid >> 14, b = (gid >> 10) & 15, j = gid & 1023;
    const float* H = l ? Hseq1 : Hseq0;
    out[LOGITS_SZ + gid] = H[(size_t)((SEQ - 1) * BATCH + b) * HIDDEN + j];
    out[LOGITS_SZ + 32768 + gid] = c_ws[gid];
}

// ---------------- launch ----------------
extern "C" void kernel_launch(void* const* d_in, const int* in_sizes, int n_in,
                              void* d_out, int out_size, void* d_ws, size_t ws_size,
                              hipStream_t stream) {
    const int* x = (const int*)d_in[0];
    const float* h0 = (const float*)d_in[1];
    const float* c0 = (const float*)d_in[2];
    const float* emb = (const float*)d_in[3];
    const float* W_ih0 = (const float*)d_in[4];
    const float* W_hh0 = (const float*)d_in[5];
    const float* b_ih0 = (const float*)d_in[6];
    const float* b_hh0 = (const float*)d_in[7];
    const float* W_ih1 = (const float*)d_in[8];
    const float* W_hh1 = (const float*)d_in[9];
    const float* b_ih1 = (const float*)d_in[10];
    const float* b_hh1 = (const float*)d_in[11];
    const float* fc_W = (const float*)d_in[12];
    const float* fc_b = (const float*)d_in[13];
    float* out = (float*)d_out;
    float* ws = (float*)d_ws;

    // workspace layout (float offsets) — WT0/WT1 regions now only host the h scratch buffer
    const size_t OFF_WT0 = 0;                                  // free (scratch h buffer)
    const size_t OFF_WT1 = OFF_WT0 + (size_t)GATES * HIDDEN;
    const size_t OFF_X0 = OFF_WT1 + (size_t)GATES * HIDDEN;    // 4096*512  (reused: Hseq1 bf16)
    const size_t OFF_G = OFF_X0 + (size_t)MROWS * EMBED;       // 4096*4096 (reused: fc_W bf16)
    const size_t OFF_H0S = OFF_G + (size_t)MROWS * GATES;      // 4096*1024
    const size_t OFF_H1S = OFF_H0S + (size_t)MROWS * HIDDEN;   // 4096*1024
    const size_t OFF_PARTS = OFF_H1S + (size_t)MROWS * HIDDEN; // (unused now)
    const size_t OFF_C = OFF_PARTS + (size_t)8 * BATCH * GATES;
    const size_t OFF_HT0 = OFF_C + 2 * BATCH * HIDDEN;
    const size_t OFF_HT1 = OFF_HT0 + (size_t)HIDDEN * BATCH;

    init_state<<<128, 256, 0, stream>>>(h0, c0, ws + OFF_C, ws + OFF_HT0, ws + OFF_HT1);
    embed_kernel<<<MROWS, 128, 0, stream>>>(x, emb, ws + OFF_X0);

    // layer 0: input projection for all timesteps, then persistent recurrence
    gemm_bt<<<dim3(GATES / 128, MROWS / 128), 256, 0, stream>>>(
        ws + OFF_X0, W_ih0, b_ih0, b_hh0, ws + OFF_G, MROWS, GATES, EMBED, 0);
    {
        const float* Gp = ws + OFF_G;
        const float* ci = c0;
        float* co = ws + OFF_C;
        float* hs = ws + OFF_H0S;
        float* hbA = ws + OFF_HT0;
        float* hbB = ws + OFF_WT0;
        void* args[] = {(void*)&W_hh0, (void*)&Gp, (void*)&ci, (void*)&co,
                        (void*)&hs, (void*)&hbA, (void*)&hbB};
        hipLaunchCooperativeKernel((void*)lstm_layer_persistent, dim3(RBLOCKS),
                                   dim3(RTHREADS), args, 0, stream);
    }

    // layer 1
    gemm_bt<<<dim3(GATES / 128, MROWS / 128), 256, 0, stream>>>(
        ws + OFF_H0S, W_ih1, b_ih1, b_hh1, ws + OFF_G, MROWS, GATES, HIDDEN, 0);
    {
        const float* Gp = ws + OFF_G;
        const float* ci = c0 + BATCH * HIDDEN;
        float* co = ws + OFF_C + BATCH * HIDDEN;
        float* hs = ws + OFF_H1S;
        float* hbA = ws + OFF_HT1;
        float* hbB = ws + OFF_WT0;
        void* args[] = {(void*)&W_hh1, (void*)&Gp, (void*)&ci, (void*)&co,
                        (void*)&hs, (void*)&hbA, (void*)&hbB};
        hipLaunchCooperativeKernel((void*)lstm_layer_persistent, dim3(RBLOCKS),
                                   dim3(RTHREADS), args, 0, stream);
    }

    // FC via bf16 MFMA: convert operands (G and X0 are dead now), then MFMA GEMM.
    f32_to_bf16_kernel<<<4096, 256, 0, stream>>>(fc_W, (u16*)(ws + OFF_G), VOCAB * HIDDEN / 8);
    f32_to_bf16_kernel<<<2048, 256, 0, stream>>>(ws + OFF_H1S, (u16*)(ws + OFF_X0),
                                                 MROWS * HIDDEN / 8);
    fc_mfma<<<dim3(VOCAB / 128, MROWS / 128), 256, 0, stream>>>(
        (const u16*)(ws + OFF_X0), (const u16*)(ws + OFF_G), fc_b, out);

    write_tails<<<128, 256, 0, stream>>>(ws + OFF_H0S, ws + OFF_H1S, ws + OFF_C, out);
}

// Round 3
// 10206.310 us; speedup vs baseline: 3.7953x; 3.7953x over previous
//
#include <hip/hip_runtime.h>
#include <hip/hip_bf16.h>
#include <cmath>

// Problem constants
#define BATCH 16
#define SEQ 256
#define EMBED 512
#define HIDDEN 1024
#define GATES 4096       // 4*HIDDEN
#define VOCAB 32000
#define MROWS 4096       // BATCH*SEQ
#define LOGITS_SZ 131072000  // 16*256*32000

#define RBLOCKS 256
#define RTHREADS 512

typedef unsigned int u32;
typedef unsigned short u16;
typedef __attribute__((ext_vector_type(8))) short bf16x8;
typedef __attribute__((ext_vector_type(4))) float f32x4;

#define AS1 __attribute__((address_space(1)))
#define AS3 __attribute__((address_space(3)))

// ---------------- embedding gather ----------------
__global__ void embed_kernel(const int* __restrict__ x, const float* __restrict__ emb,
                             float* __restrict__ X0) {
    int r = blockIdx.x;            // r = s*16 + b
    int s = r >> 4, b = r & 15;
    int tok = x[b * SEQ + s];
    const float4* src = (const float4*)(emb + (size_t)tok * EMBED);
    float4* dst = (float4*)(X0 + (size_t)r * EMBED);
    for (int i = threadIdx.x; i < EMBED / 4; i += blockDim.x) dst[i] = src[i];
}

// ---------------- fp32 GEMM: C[M,N] = A[M,K] @ B[N,K]^T + b1 + b2 ----------------
__global__ __launch_bounds__(256) void gemm_bt(
    const float* __restrict__ A, const float* __restrict__ B,
    const float* __restrict__ b1, const float* __restrict__ b2,
    float* __restrict__ C, int M, int N, int K, int perm) {
    __shared__ float As[8][128];
    __shared__ float Bs[8][128];
    int tid = threadIdx.x;
    int bm = blockIdx.y, bn = blockIdx.x;
    int arow = tid >> 1;              // 0..127
    int ak4 = (tid & 1) * 4;          // 0 or 4
    const float* Ag = A + (size_t)(bm * 128 + arow) * K + ak4;
    const float* Bg = B + (size_t)(bn * 128 + arow) * K + ak4;
    int tx = tid & 15, ty = tid >> 4;

    float acc[8][8];
#pragma unroll
    for (int i = 0; i < 8; i++)
#pragma unroll
        for (int j = 0; j < 8; j++) acc[i][j] = 0.f;

    for (int k0 = 0; k0 < K; k0 += 8) {
        float4 a4 = *(const float4*)(Ag + k0);
        float4 b4 = *(const float4*)(Bg + k0);
        __syncthreads();
        As[ak4 + 0][arow] = a4.x; As[ak4 + 1][arow] = a4.y;
        As[ak4 + 2][arow] = a4.z; As[ak4 + 3][arow] = a4.w;
        Bs[ak4 + 0][arow] = b4.x; Bs[ak4 + 1][arow] = b4.y;
        Bs[ak4 + 2][arow] = b4.z; Bs[ak4 + 3][arow] = b4.w;
        __syncthreads();
#pragma unroll
        for (int k = 0; k < 8; k++) {
            float av[8], bv[8];
            *(float4*)(av + 0) = *(const float4*)&As[k][ty * 8 + 0];
            *(float4*)(av + 4) = *(const float4*)&As[k][ty * 8 + 4];
            *(float4*)(bv + 0) = *(const float4*)&Bs[k][tx * 8 + 0];
            *(float4*)(bv + 4) = *(const float4*)&Bs[k][tx * 8 + 4];
#pragma unroll
            for (int i = 0; i < 8; i++)
#pragma unroll
                for (int j = 0; j < 8; j++) acc[i][j] += av[i] * bv[j];
        }
    }

#pragma unroll
    for (int i = 0; i < 8; i++) {
        int r = bm * 128 + ty * 8 + i;
        int orow = perm ? ((r & 15) * SEQ + (r >> 4)) : r;
#pragma unroll
        for (int j = 0; j < 8; j += 4) {
            int c = bn * 128 + tx * 8 + j;
            float4 v;
            float bb0 = (b1 ? b1[c + 0] : 0.f) + (b2 ? b2[c + 0] : 0.f);
            float bb1 = (b1 ? b1[c + 1] : 0.f) + (b2 ? b2[c + 1] : 0.f);
            float bb2 = (b1 ? b1[c + 2] : 0.f) + (b2 ? b2[c + 2] : 0.f);
            float bb3 = (b1 ? b1[c + 3] : 0.f) + (b2 ? b2[c + 3] : 0.f);
            v.x = acc[i][j + 0] + bb0;
            v.y = acc[i][j + 1] + bb1;
            v.z = acc[i][j + 2] + bb2;
            v.w = acc[i][j + 3] + bb3;
            *(float4*)&C[(size_t)orow * N + c] = v;
        }
    }
}

// ---------------- fp32 -> bf16 conversion (RNE) ----------------
__device__ __forceinline__ u32 f2bf(float f) {
    u32 u = __float_as_uint(f);
    return (u + 0x7fffu + ((u >> 16) & 1u)) >> 16;
}

__global__ __launch_bounds__(256) void f32_to_bf16_kernel(
    const float* __restrict__ in, u16* __restrict__ out, int n8) {
    for (int i = blockIdx.x * 256 + threadIdx.x; i < n8; i += gridDim.x * 256) {
        float4 a = ((const float4*)in)[2 * (size_t)i + 0];
        float4 b = ((const float4*)in)[2 * (size_t)i + 1];
        uint4 o;
        o.x = f2bf(a.x) | (f2bf(a.y) << 16);
        o.y = f2bf(a.z) | (f2bf(a.w) << 16);
        o.z = f2bf(b.x) | (f2bf(b.y) << 16);
        o.w = f2bf(b.z) | (f2bf(b.w) << 16);
        ((uint4*)out)[i] = o;
    }
}

// ---------------- bf16 MFMA FC GEMM ----------------
__global__ __launch_bounds__(256) void fc_mfma(
    const u16* __restrict__ Abf,   // [MROWS][1024] bf16
    const u16* __restrict__ Bbf,   // [VOCAB][1024] bf16
    const float* __restrict__ bias,
    float* __restrict__ C) {
    const int K = HIDDEN;          // 1024
    const int N = VOCAB;
    __shared__ char smem[16384];   // As 8KB + Bs 8KB
    char* As = smem;
    char* Bs = smem + 8192;

    int tid = threadIdx.x;
    int w = tid >> 6, l = tid & 63;
    int bn = blockIdx.x, bm = blockIdx.y;
    int wr = w >> 1, wc = w & 1;
    int lr = l & 15, lk = l >> 4;

    f32x4 acc[4][4];
#pragma unroll
    for (int m = 0; m < 4; m++)
#pragma unroll
        for (int n = 0; n < 4; n++) acc[m][n] = {0.f, 0.f, 0.f, 0.f};

    int srow = tid >> 2, skc = (tid & 3) * 8;
    const u16* ga0 = Abf + (size_t)(bm * 128 + srow) * K + skc;
    const u16* ga1 = Abf + (size_t)(bm * 128 + 64 + srow) * K + skc;
    const u16* gb0 = Bbf + (size_t)(bn * 128 + srow) * K + skc;
    const u16* gb1 = Bbf + (size_t)(bn * 128 + 64 + srow) * K + skc;
    char* la0 = As + w * 1024;
    char* la1 = As + 4096 + w * 1024;
    char* lb0 = Bs + w * 1024;
    char* lb1 = Bs + 4096 + w * 1024;

    int afo[4], bfo[4];
#pragma unroll
    for (int m = 0; m < 4; m++) afo[m] = (wr * 64 + m * 16 + lr) * 64 + lk * 16;
#pragma unroll
    for (int n = 0; n < 4; n++) bfo[n] = (wc * 64 + n * 16 + lr) * 64 + lk * 16;

    for (int k0 = 0; k0 < K; k0 += 32) {
        __syncthreads();
        __builtin_amdgcn_global_load_lds((const AS1 u32*)(const void*)(ga0 + k0),
                                         (AS3 u32*)(void*)la0, 16, 0, 0);
        __builtin_amdgcn_global_load_lds((const AS1 u32*)(const void*)(ga1 + k0),
                                         (AS3 u32*)(void*)la1, 16, 0, 0);
        __builtin_amdgcn_global_load_lds((const AS1 u32*)(const void*)(gb0 + k0),
                                         (AS3 u32*)(void*)lb0, 16, 0, 0);
        __builtin_amdgcn_global_load_lds((const AS1 u32*)(const void*)(gb1 + k0),
                                         (AS3 u32*)(void*)lb1, 16, 0, 0);
        __syncthreads();

        bf16x8 af[4], bfr[4];
#pragma unroll
        for (int m = 0; m < 4; m++) af[m] = *(const bf16x8*)(As + afo[m]);
#pragma unroll
        for (int n = 0; n < 4; n++) bfr[n] = *(const bf16x8*)(Bs + bfo[n]);
#pragma unroll
        for (int m = 0; m < 4; m++)
#pragma unroll
            for (int n = 0; n < 4; n++)
                acc[m][n] = __builtin_amdgcn_mfma_f32_16x16x32_bf16(
                    af[m], bfr[n], acc[m][n], 0, 0, 0);
    }

    int rbase = bm * 128 + wr * 64 + lk * 4;
    int cbase = bn * 128 + wc * 64 + lr;
#pragma unroll
    for (int m = 0; m < 4; m++) {
#pragma unroll
        for (int n = 0; n < 4; n++) {
            int c = cbase + n * 16;
            float bb = bias[c];
#pragma unroll
            for (int j = 0; j < 4; j++) {
                int r = rbase + m * 16 + j;
                int orow = (r & 15) * SEQ + (r >> 4);   // [B,S,V] layout
                C[(size_t)orow * N + c] = acc[m][n][j] + bb;
            }
        }
    }
}

// ---------------- persistent LSTM layer with flag barrier ----------------
// 256 blocks x 512 threads. Block owns 4 hidden units (16 gate cols) over full K.
// Weights in registers; h parity-double-buffered in global; c in registers.
// Barrier: per-block RELEASE store of epoch into own slot; wave0 polls all 256.
__global__ __launch_bounds__(RTHREADS) void lstm_layer_persistent(
    const float* __restrict__ Whh,    // [4096][1024] row-major
    const float* __restrict__ G,      // [4096][4096] rows t*16+b
    const float* __restrict__ c_init, // [16][1024]
    float* __restrict__ c_out,        // [16][1024]
    float* __restrict__ Hseq,         // [4096][1024] rows t*16+b
    float* __restrict__ hb0,          // [1024][16] parity-0 h (pre-loaded with h0)
    float* __restrict__ hb1,          // [1024][16] parity-1 h (scratch)
    u32* __restrict__ arrive,         // [256] monotone epoch slots (zeroed)
    int ebase) {
    __shared__ float Hl[1024][16];      // 64 KB: h[k][b]
    __shared__ float Pl[32][16][17];    // 34.8 KB: partials [kc][c][b] (+pad, <=2-way)
    __shared__ float Sl[16][17];        // gate sums [col][b]

    const int tid = threadIdx.x;
    const int bid = blockIdx.x;
    const int j0 = bid * 4;                  // 4 hidden units per block
    const int c = tid & 15;                  // col within block: c = g*4 + jj
    const int kc = tid >> 4;                 // 0..31, k-chunk (interleaved, stride 32)
    const int nrow = (c >> 2) * HIDDEN + j0 + (c & 3);

    // W_hh slice into registers: thread owns col c, k = kc + 32*i (i=0..31)
    float w[32];
    {
        const float* wr = Whh + (size_t)nrow * HIDDEN + kc;
#pragma unroll
        for (int i = 0; i < 32; i++) w[i] = wr[i * 32];
    }

    const int ub = tid >> 2, ujj = tid & 3;  // update mapping for tid<64
    float creg = 0.f;
    if (tid < 64) creg = c_init[ub * HIDDEN + j0 + ujj];

    for (int t = 0; t < SEQ; t++) {
        // prefetch this step's input-projection gates
        float gp0, gp1, gp2, gp3;
        if (tid < 64) {
            const float* gp = G + ((size_t)(t * BATCH + ub)) * GATES + j0 + ujj;
            gp0 = gp[0]; gp1 = gp[HIDDEN]; gp2 = gp[2 * HIDDEN]; gp3 = gp[3 * HIDDEN];
        }
        // stage h_t into LDS, lane-contiguous (conflict-free, coalesced)
        {
            const float4* src = (const float4*)((t & 1) ? hb1 : hb0);
            float4* dst = (float4*)&Hl[0][0];
#pragma unroll
            for (int i = 0; i < 8; i++) dst[i * 512 + tid] = src[i * 512 + tid];
        }
        __syncthreads();

        // partial recurrent GEMM: acc[b] = sum_{k in chunk} W[c][k] * h[k][b]
        float acc[16];
#pragma unroll
        for (int b = 0; b < 16; b++) acc[b] = 0.f;
#pragma unroll
        for (int i = 0; i < 32; i++) {
            const float wv = w[i];
            const float4* hp4 = (const float4*)&Hl[kc + i * 32][0];
            float4 h0v = hp4[0], h1v = hp4[1], h2v = hp4[2], h3v = hp4[3];
            acc[0] += wv * h0v.x;  acc[1] += wv * h0v.y;
            acc[2] += wv * h0v.z;  acc[3] += wv * h0v.w;
            acc[4] += wv * h1v.x;  acc[5] += wv * h1v.y;
            acc[6] += wv * h1v.z;  acc[7] += wv * h1v.w;
            acc[8] += wv * h2v.x;  acc[9] += wv * h2v.y;
            acc[10] += wv * h2v.z; acc[11] += wv * h2v.w;
            acc[12] += wv * h3v.x; acc[13] += wv * h3v.y;
            acc[14] += wv * h3v.z; acc[15] += wv * h3v.w;
        }
#pragma unroll
        for (int b = 0; b < 16; b++) Pl[kc][c][b] = acc[b];
        __syncthreads();

        // reduce 32 k-chunk partials per (col, b)
        if (tid < 256) {
            const int c2 = tid & 15, b2 = tid >> 4;
            float s = 0.f;
#pragma unroll
            for (int q = 0; q < 32; q++) s += Pl[q][c2][b2];
            Sl[c2][b2] = s;
        }
        __syncthreads();

        // LSTM pointwise update for this block's 4 hidden units x 16 batches
        if (tid < 64) {
            const float gi_ = gp0 + Sl[ujj][ub];
            const float gf_ = gp1 + Sl[4 + ujj][ub];
            const float gg_ = gp2 + Sl[8 + ujj][ub];
            const float go_ = gp3 + Sl[12 + ujj][ub];
            const float ig = 1.f / (1.f + __expf(-gi_));
            const float fg = 1.f / (1.f + __expf(-gf_));
            const float gt = tanhf(gg_);
            const float og = 1.f / (1.f + __expf(-go_));
            creg = fg * creg + ig * gt;
            const float h = og * tanhf(creg);
            Hseq[((size_t)(t * BATCH + ub)) * HIDDEN + j0 + ujj] = h;
            float* hbn = (t & 1) ? hb0 : hb1;
            hbn[(j0 + ujj) * BATCH + ub] = h;
        }
        __syncthreads();   // drains h stores (vmcnt0 before s_barrier)

        if (t < SEQ - 1) {
            const u32 epoch = (u32)(ebase + t + 1);
            if (tid == 0)
                __hip_atomic_store(&arrive[bid], epoch, __ATOMIC_RELEASE,
                                   __HIP_MEMORY_SCOPE_AGENT);
            if (tid < 64) {   // wave 0 polls all 256 slots, 4 per lane
                const int i0 = tid * 4;
                for (;;) {
                    u32 a0 = __hip_atomic_load(&arrive[i0 + 0], __ATOMIC_RELAXED,
                                               __HIP_MEMORY_SCOPE_AGENT);
                    u32 a1 = __hip_atomic_load(&arrive[i0 + 1], __ATOMIC_RELAXED,
                                               __HIP_MEMORY_SCOPE_AGENT);
                    u32 a2 = __hip_atomic_load(&arrive[i0 + 2], __ATOMIC_RELAXED,
                                               __HIP_MEMORY_SCOPE_AGENT);
                    u32 a3 = __hip_atomic_load(&arrive[i0 + 3], __ATOMIC_RELAXED,
                                               __HIP_MEMORY_SCOPE_AGENT);
                    u32 m01 = a0 < a1 ? a0 : a1;
                    u32 m23 = a2 < a3 ? a2 : a3;
                    u32 mn = m01 < m23 ? m01 : m23;
                    if (__all(mn >= epoch)) break;
                    __builtin_amdgcn_s_sleep(2);
                }
                __threadfence();   // acquire: invalidate L1/L2 before reading fresh h
            }
            __syncthreads();
        }
    }
    if (tid < 64) c_out[ub * HIDDEN + j0 + ujj] = creg;
}

// ---------------- init & tails ----------------
__global__ void init_state(const float* __restrict__ h0, const float* __restrict__ c0,
                           float* __restrict__ c_ws, float* __restrict__ ht0,
                           float* __restrict__ ht1, u32* __restrict__ arrive) {
    int gid = blockIdx.x * 256 + threadIdx.x;  // 32768
    if (gid < 256) arrive[gid] = 0;
    c_ws[gid] = c0[gid];
    int l = gid >> 14, b = (gid >> 10) & 15, j = gid & 1023;
    float h = h0[gid];
    float* htp = l ? ht1 : ht0;
    htp[j * BATCH + b] = h;
}

__global__ void write_tails(const float* __restrict__ Hseq0, const float* __restrict__ Hseq1,
                            const float* __restrict__ c_ws, float* __restrict__ out) {
    int gid = blockIdx.x * 256 + threadIdx.x;  // 32768
    int l = gid >> 14, b = (gid >> 10) & 15, j = gid & 1023;
    const float* H = l ? Hseq1 : Hseq0;
    out[LOGITS_SZ + gid] = H[(size_t)((SEQ - 1) * BATCH + b) * HIDDEN + j];
    out[LOGITS_SZ + 32768 + gid] = c_ws[gid];
}

// ---------------- launch ----------------
extern "C" void kernel_launch(void* const* d_in, const int* in_sizes, int n_in,
                              void* d_out, int out_size, void* d_ws, size_t ws_size,
                              hipStream_t stream) {
    const int* x = (const int*)d_in[0];
    const float* h0 = (const float*)d_in[1];
    const float* c0 = (const float*)d_in[2];
    const float* emb = (const float*)d_in[3];
    const float* W_ih0 = (const float*)d_in[4];
    const float* W_hh0 = (const float*)d_in[5];
    const float* b_ih0 = (const float*)d_in[6];
    const float* b_hh0 = (const float*)d_in[7];
    const float* W_ih1 = (const float*)d_in[8];
    const float* W_hh1 = (const float*)d_in[9];
    const float* b_ih1 = (const float*)d_in[10];
    const float* b_hh1 = (const float*)d_in[11];
    const float* fc_W = (const float*)d_in[12];
    const float* fc_b = (const float*)d_in[13];
    float* out = (float*)d_out;
    float* ws = (float*)d_ws;

    // workspace layout (float offsets)
    const size_t OFF_WT0 = 0;                                  // scratch h buffer
    const size_t OFF_WT1 = OFF_WT0 + (size_t)GATES * HIDDEN;   // barrier slots
    const size_t OFF_X0 = OFF_WT1 + (size_t)GATES * HIDDEN;    // 4096*512 (reused: Hseq1 bf16)
    const size_t OFF_G = OFF_X0 + (size_t)MROWS * EMBED;       // 4096*4096 (reused: fc_W bf16)
    const size_t OFF_H0S = OFF_G + (size_t)MROWS * GATES;
    const size_t OFF_H1S = OFF_H0S + (size_t)MROWS * HIDDEN;
    const size_t OFF_PARTS = OFF_H1S + (size_t)MROWS * HIDDEN;
    const size_t OFF_C = OFF_PARTS + (size_t)8 * BATCH * GATES;
    const size_t OFF_HT0 = OFF_C + 2 * BATCH * HIDDEN;
    const size_t OFF_HT1 = OFF_HT0 + (size_t)HIDDEN * BATCH;

    u32* arrive = (u32*)(ws + OFF_WT1);

    init_state<<<128, 256, 0, stream>>>(h0, c0, ws + OFF_C, ws + OFF_HT0,
                                        ws + OFF_HT1, arrive);
    embed_kernel<<<MROWS, 128, 0, stream>>>(x, emb, ws + OFF_X0);

    // layer 0: input projection for all timesteps, then persistent recurrence
    gemm_bt<<<dim3(GATES / 128, MROWS / 128), 256, 0, stream>>>(
        ws + OFF_X0, W_ih0, b_ih0, b_hh0, ws + OFF_G, MROWS, GATES, EMBED, 0);
    {
        const float* Gp = ws + OFF_G;
        const float* ci = c0;
        float* co = ws + OFF_C;
        float* hs = ws + OFF_H0S;
        float* hbA = ws + OFF_HT0;
        float* hbB = ws + OFF_WT0;
        int ebase = 0;
        void* args[] = {(void*)&W_hh0, (void*)&Gp, (void*)&ci, (void*)&co,
                        (void*)&hs, (void*)&hbA, (void*)&hbB, (void*)&arrive,
                        (void*)&ebase};
        hipLaunchCooperativeKernel((void*)lstm_layer_persistent, dim3(RBLOCKS),
                                   dim3(RTHREADS), args, 0, stream);
    }

    // layer 1
    gemm_bt<<<dim3(GATES / 128, MROWS / 128), 256, 0, stream>>>(
        ws + OFF_H0S, W_ih1, b_ih1, b_hh1, ws + OFF_G, MROWS, GATES, HIDDEN, 0);
    {
        const float* Gp = ws + OFF_G;
        const float* ci = c0 + BATCH * HIDDEN;
        float* co = ws + OFF_C + BATCH * HIDDEN;
        float* hs = ws + OFF_H1S;
        float* hbA = ws + OFF_HT1;
        float* hbB = ws + OFF_WT0;
        int ebase = SEQ;
        void* args[] = {(void*)&W_hh1, (void*)&Gp, (void*)&ci, (void*)&co,
                        (void*)&hs, (void*)&hbA, (void*)&hbB, (void*)&arrive,
                        (void*)&ebase};
        hipLaunchCooperativeKernel((void*)lstm_layer_persistent, dim3(RBLOCKS),
                                   dim3(RTHREADS), args, 0, stream);
    }

    // FC via bf16 MFMA: convert operands (G and X0 are dead now), then MFMA GEMM.
    f32_to_bf16_kernel<<<4096, 256, 0, stream>>>(fc_W, (u16*)(ws + OFF_G), VOCAB * HIDDEN / 8);
    f32_to_bf16_kernel<<<2048, 256, 0, stream>>>(ws + OFF_H1S, (u16*)(ws + OFF_X0),
                                                 MROWS * HIDDEN / 8);
    fc_mfma<<<dim3(VOCAB / 128, MROWS / 128), 256, 0, stream>>>(
        (const u16*)(ws + OFF_X0), (const u16*)(ws + OFF_G), fc_b, out);

    write_tails<<<128, 256, 0, stream>>>(ws + OFF_H0S, ws + OFF_H1S, ws + OFF_C, out);
}

// Round 4
// 6147.467 us; speedup vs baseline: 6.3012x; 1.6602x over previous
//
#include <hip/hip_runtime.h>
#include <hip/hip_bf16.h>
#include <cmath>

// Problem constants
#define BATCH 16
#define SEQ 256
#define EMBED 512
#define HIDDEN 1024
#define GATES 4096       // 4*HIDDEN
#define VOCAB 32000
#define MROWS 4096       // BATCH*SEQ
#define LOGITS_SZ 131072000  // 16*256*32000

#define RBLOCKS 256
#define RTHREADS 512

typedef unsigned int u32;
typedef unsigned short u16;
typedef unsigned long long u64;
typedef __attribute__((ext_vector_type(8))) short bf16x8;
typedef __attribute__((ext_vector_type(4))) float f32x4;

#define AS1 __attribute__((address_space(1)))
#define AS3 __attribute__((address_space(3)))

// ---------------- embedding gather ----------------
__global__ void embed_kernel(const int* __restrict__ x, const float* __restrict__ emb,
                             float* __restrict__ X0) {
    int r = blockIdx.x;            // r = s*16 + b
    int s = r >> 4, b = r & 15;
    int tok = x[b * SEQ + s];
    const float4* src = (const float4*)(emb + (size_t)tok * EMBED);
    float4* dst = (float4*)(X0 + (size_t)r * EMBED);
    for (int i = threadIdx.x; i < EMBED / 4; i += blockDim.x) dst[i] = src[i];
}

// ---------------- fp32 GEMM: C[M,N] = A[M,K] @ B[N,K]^T + b1 + b2 ----------------
__global__ __launch_bounds__(256) void gemm_bt(
    const float* __restrict__ A, const float* __restrict__ B,
    const float* __restrict__ b1, const float* __restrict__ b2,
    float* __restrict__ C, int M, int N, int K, int perm) {
    __shared__ float As[8][128];
    __shared__ float Bs[8][128];
    int tid = threadIdx.x;
    int bm = blockIdx.y, bn = blockIdx.x;
    int arow = tid >> 1;              // 0..127
    int ak4 = (tid & 1) * 4;          // 0 or 4
    const float* Ag = A + (size_t)(bm * 128 + arow) * K + ak4;
    const float* Bg = B + (size_t)(bn * 128 + arow) * K + ak4;
    int tx = tid & 15, ty = tid >> 4;

    float acc[8][8];
#pragma unroll
    for (int i = 0; i < 8; i++)
#pragma unroll
        for (int j = 0; j < 8; j++) acc[i][j] = 0.f;

    for (int k0 = 0; k0 < K; k0 += 8) {
        float4 a4 = *(const float4*)(Ag + k0);
        float4 b4 = *(const float4*)(Bg + k0);
        __syncthreads();
        As[ak4 + 0][arow] = a4.x; As[ak4 + 1][arow] = a4.y;
        As[ak4 + 2][arow] = a4.z; As[ak4 + 3][arow] = a4.w;
        Bs[ak4 + 0][arow] = b4.x; Bs[ak4 + 1][arow] = b4.y;
        Bs[ak4 + 2][arow] = b4.z; Bs[ak4 + 3][arow] = b4.w;
        __syncthreads();
#pragma unroll
        for (int k = 0; k < 8; k++) {
            float av[8], bv[8];
            *(float4*)(av + 0) = *(const float4*)&As[k][ty * 8 + 0];
            *(float4*)(av + 4) = *(const float4*)&As[k][ty * 8 + 4];
            *(float4*)(bv + 0) = *(const float4*)&Bs[k][tx * 8 + 0];
            *(float4*)(bv + 4) = *(const float4*)&Bs[k][tx * 8 + 4];
#pragma unroll
            for (int i = 0; i < 8; i++)
#pragma unroll
                for (int j = 0; j < 8; j++) acc[i][j] += av[i] * bv[j];
        }
    }

#pragma unroll
    for (int i = 0; i < 8; i++) {
        int r = bm * 128 + ty * 8 + i;
        int orow = perm ? ((r & 15) * SEQ + (r >> 4)) : r;
#pragma unroll
        for (int j = 0; j < 8; j += 4) {
            int c = bn * 128 + tx * 8 + j;
            float4 v;
            float bb0 = (b1 ? b1[c + 0] : 0.f) + (b2 ? b2[c + 0] : 0.f);
            float bb1 = (b1 ? b1[c + 1] : 0.f) + (b2 ? b2[c + 1] : 0.f);
            float bb2 = (b1 ? b1[c + 2] : 0.f) + (b2 ? b2[c + 2] : 0.f);
            float bb3 = (b1 ? b1[c + 3] : 0.f) + (b2 ? b2[c + 3] : 0.f);
            v.x = acc[i][j + 0] + bb0;
            v.y = acc[i][j + 1] + bb1;
            v.z = acc[i][j + 2] + bb2;
            v.w = acc[i][j + 3] + bb3;
            *(float4*)&C[(size_t)orow * N + c] = v;
        }
    }
}

// ---------------- fp32 -> bf16 conversion (RNE) ----------------
__device__ __forceinline__ u32 f2bf(float f) {
    u32 u = __float_as_uint(f);
    return (u + 0x7fffu + ((u >> 16) & 1u)) >> 16;
}

__global__ __launch_bounds__(256) void f32_to_bf16_kernel(
    const float* __restrict__ in, u16* __restrict__ out, int n8) {
    for (int i = blockIdx.x * 256 + threadIdx.x; i < n8; i += gridDim.x * 256) {
        float4 a = ((const float4*)in)[2 * (size_t)i + 0];
        float4 b = ((const float4*)in)[2 * (size_t)i + 1];
        uint4 o;
        o.x = f2bf(a.x) | (f2bf(a.y) << 16);
        o.y = f2bf(a.z) | (f2bf(a.w) << 16);
        o.z = f2bf(b.x) | (f2bf(b.y) << 16);
        o.w = f2bf(b.z) | (f2bf(b.w) << 16);
        ((uint4*)out)[i] = o;
    }
}

// ---------------- bf16 MFMA FC GEMM ----------------
__global__ __launch_bounds__(256) void fc_mfma(
    const u16* __restrict__ Abf,   // [MROWS][1024] bf16
    const u16* __restrict__ Bbf,   // [VOCAB][1024] bf16
    const float* __restrict__ bias,
    float* __restrict__ C) {
    const int K = HIDDEN;          // 1024
    const int N = VOCAB;
    __shared__ char smem[16384];   // As 8KB + Bs 8KB
    char* As = smem;
    char* Bs = smem + 8192;

    int tid = threadIdx.x;
    int w = tid >> 6, l = tid & 63;
    int bn = blockIdx.x, bm = blockIdx.y;
    int wr = w >> 1, wc = w & 1;
    int lr = l & 15, lk = l >> 4;

    f32x4 acc[4][4];
#pragma unroll
    for (int m = 0; m < 4; m++)
#pragma unroll
        for (int n = 0; n < 4; n++) acc[m][n] = {0.f, 0.f, 0.f, 0.f};

    int srow = tid >> 2, skc = (tid & 3) * 8;
    const u16* ga0 = Abf + (size_t)(bm * 128 + srow) * K + skc;
    const u16* ga1 = Abf + (size_t)(bm * 128 + 64 + srow) * K + skc;
    const u16* gb0 = Bbf + (size_t)(bn * 128 + srow) * K + skc;
    const u16* gb1 = Bbf + (size_t)(bn * 128 + 64 + srow) * K + skc;
    char* la0 = As + w * 1024;
    char* la1 = As + 4096 + w * 1024;
    char* lb0 = Bs + w * 1024;
    char* lb1 = Bs + 4096 + w * 1024;

    int afo[4], bfo[4];
#pragma unroll
    for (int m = 0; m < 4; m++) afo[m] = (wr * 64 + m * 16 + lr) * 64 + lk * 16;
#pragma unroll
    for (int n = 0; n < 4; n++) bfo[n] = (wc * 64 + n * 16 + lr) * 64 + lk * 16;

    for (int k0 = 0; k0 < K; k0 += 32) {
        __syncthreads();
        __builtin_amdgcn_global_load_lds((const AS1 u32*)(const void*)(ga0 + k0),
                                         (AS3 u32*)(void*)la0, 16, 0, 0);
        __builtin_amdgcn_global_load_lds((const AS1 u32*)(const void*)(ga1 + k0),
                                         (AS3 u32*)(void*)la1, 16, 0, 0);
        __builtin_amdgcn_global_load_lds((const AS1 u32*)(const void*)(gb0 + k0),
                                         (AS3 u32*)(void*)lb0, 16, 0, 0);
        __builtin_amdgcn_global_load_lds((const AS1 u32*)(const void*)(gb1 + k0),
                                         (AS3 u32*)(void*)lb1, 16, 0, 0);
        __syncthreads();

        bf16x8 af[4], bfr[4];
#pragma unroll
        for (int m = 0; m < 4; m++) af[m] = *(const bf16x8*)(As + afo[m]);
#pragma unroll
        for (int n = 0; n < 4; n++) bfr[n] = *(const bf16x8*)(Bs + bfo[n]);
#pragma unroll
        for (int m = 0; m < 4; m++)
#pragma unroll
            for (int n = 0; n < 4; n++)
                acc[m][n] = __builtin_amdgcn_mfma_f32_16x16x32_bf16(
                    af[m], bfr[n], acc[m][n], 0, 0, 0);
    }

    int rbase = bm * 128 + wr * 64 + lk * 4;
    int cbase = bn * 128 + wc * 64 + lr;
#pragma unroll
    for (int m = 0; m < 4; m++) {
#pragma unroll
        for (int n = 0; n < 4; n++) {
            int c = cbase + n * 16;
            float bb = bias[c];
#pragma unroll
            for (int j = 0; j < 4; j++) {
                int r = rbase + m * 16 + j;
                int orow = (r & 15) * SEQ + (r >> 4);   // [B,S,V] layout
                C[(size_t)orow * N + c] = acc[m][n][j] + bb;
            }
        }
    }
}

// ---------------- persistent LSTM layer, coherent-bit h exchange ----------------
// 256 blocks x 512 threads. Block owns 4 hidden units (16 gate cols) over full K.
// Weights in registers; h exchanged via RELAXED-AGENT atomics (sc0/sc1 -> L3,
// no L2 writeback/invalidate); arrive-flag barrier, no fences.
__global__ __launch_bounds__(RTHREADS) void lstm_layer_persistent(
    const float* __restrict__ Whh,    // [4096][1024] row-major
    const float* __restrict__ G,      // [4096][4096] rows t*16+b
    const float* __restrict__ c_init, // [16][1024]
    float* __restrict__ c_out,        // [16][1024]
    float* __restrict__ Hseq,         // [4096][1024] rows t*16+b
    float* __restrict__ hb0,          // [1024][16] parity-0 h (pre-loaded with h0)
    float* __restrict__ hb1,          // [1024][16] parity-1 h (scratch)
    u32* __restrict__ arrive,         // [256] monotone epoch slots (zeroed)
    int ebase) {
    __shared__ float Hl[1024][16];      // 64 KB: h[k][b]
    __shared__ float Pl[32][16][17];    // 34.8 KB: partials [kc][c][b] (+pad)
    __shared__ float Sl[16][17];        // gate sums [col][b]

    const int tid = threadIdx.x;
    const int bid = blockIdx.x;
    const int j0 = bid * 4;                  // 4 hidden units per block
    const int c = tid & 15;                  // col within block: c = g*4 + jj
    const int kc = tid >> 4;                 // 0..31, k-chunk (interleaved, stride 32)
    const int nrow = (c >> 2) * HIDDEN + j0 + (c & 3);

    // W_hh slice into registers: thread owns col c, k = kc + 32*i (i=0..31)
    float w[32];
    {
        const float* wr = Whh + (size_t)nrow * HIDDEN + kc;
#pragma unroll
        for (int i = 0; i < 32; i++) w[i] = wr[i * 32];
    }

    const int ub = tid >> 2, ujj = tid & 3;  // update mapping for tid<64
    float creg = 0.f;
    if (tid < 64) creg = c_init[ub * HIDDEN + j0 + ujj];

    for (int t = 0; t < SEQ; t++) {
        // prefetch this step's input-projection gates
        float gp0, gp1, gp2, gp3;
        if (tid < 64) {
            const float* gp = G + ((size_t)(t * BATCH + ub)) * GATES + j0 + ujj;
            gp0 = gp[0]; gp1 = gp[HIDDEN]; gp2 = gp[2 * HIDDEN]; gp3 = gp[3 * HIDDEN];
        }
        // stage h_t into LDS via agent-scope (sc1) loads: fresh from L3, no inval.
        // 16 independent u64 loads -> back-to-back issue, latency overlapped.
        {
            const u64* src = (const u64*)((t & 1) ? hb1 : hb0);
            u64 tmp[16];
#pragma unroll
            for (int i = 0; i < 16; i++)
                tmp[i] = __hip_atomic_load(src + i * 512 + tid, __ATOMIC_RELAXED,
                                           __HIP_MEMORY_SCOPE_AGENT);
            u64* dstl = (u64*)&Hl[0][0];
#pragma unroll
            for (int i = 0; i < 16; i++) dstl[i * 512 + tid] = tmp[i];
        }
        __syncthreads();

        // partial recurrent GEMM: acc[b] = sum_{k in chunk} W[c][k] * h[k][b]
        float acc[16];
#pragma unroll
        for (int b = 0; b < 16; b++) acc[b] = 0.f;
#pragma unroll
        for (int i = 0; i < 32; i++) {
            const float wv = w[i];
            const float4* hp4 = (const float4*)&Hl[kc + i * 32][0];
            float4 h0v = hp4[0], h1v = hp4[1], h2v = hp4[2], h3v = hp4[3];
            acc[0] += wv * h0v.x;  acc[1] += wv * h0v.y;
            acc[2] += wv * h0v.z;  acc[3] += wv * h0v.w;
            acc[4] += wv * h1v.x;  acc[5] += wv * h1v.y;
            acc[6] += wv * h1v.z;  acc[7] += wv * h1v.w;
            acc[8] += wv * h2v.x;  acc[9] += wv * h2v.y;
            acc[10] += wv * h2v.z; acc[11] += wv * h2v.w;
            acc[12] += wv * h3v.x; acc[13] += wv * h3v.y;
            acc[14] += wv * h3v.z; acc[15] += wv * h3v.w;
        }
#pragma unroll
        for (int b = 0; b < 16; b++) Pl[kc][c][b] = acc[b];
        __syncthreads();

        // reduce 32 k-chunk partials per (col, b)
        if (tid < 256) {
            const int c2 = tid & 15, b2 = tid >> 4;
            float s = 0.f;
#pragma unroll
            for (int q = 0; q < 32; q++) s += Pl[q][c2][b2];
            Sl[c2][b2] = s;
        }
        __syncthreads();

        // LSTM pointwise update + barrier (all in wave 0; vmcnt orders h->arrive)
        if (tid < 64) {
            const float gi_ = gp0 + Sl[ujj][ub];
            const float gf_ = gp1 + Sl[4 + ujj][ub];
            const float gg_ = gp2 + Sl[8 + ujj][ub];
            const float go_ = gp3 + Sl[12 + ujj][ub];
            const float ig = 1.f / (1.f + __expf(-gi_));
            const float fg = 1.f / (1.f + __expf(-gf_));
            const float gt = tanhf(gg_);
            const float og = 1.f / (1.f + __expf(-go_));
            creg = fg * creg + ig * gt;
            const float h = og * tanhf(creg);
            Hseq[((size_t)(t * BATCH + ub)) * HIDDEN + j0 + ujj] = h;
            float* hbn = (t & 1) ? hb0 : hb1;
            // write-through to L3 (agent scope): visible without L2 writeback
            __hip_atomic_store(&hbn[(j0 + ujj) * BATCH + ub], h, __ATOMIC_RELAXED,
                               __HIP_MEMORY_SCOPE_AGENT);

            if (t < SEQ - 1) {
                const u32 epoch = (u32)(ebase + t + 1);
                // drain this wave's h stores to L3 before posting arrival
                asm volatile("s_waitcnt vmcnt(0)" ::: "memory");
                if (tid == 0)
                    __hip_atomic_store(&arrive[bid], epoch, __ATOMIC_RELAXED,
                                       __HIP_MEMORY_SCOPE_AGENT);
                const int i0 = tid * 4;
                for (;;) {
                    u32 a0 = __hip_atomic_load(&arrive[i0 + 0], __ATOMIC_RELAXED,
                                               __HIP_MEMORY_SCOPE_AGENT);
                    u32 a1 = __hip_atomic_load(&arrive[i0 + 1], __ATOMIC_RELAXED,
                                               __HIP_MEMORY_SCOPE_AGENT);
                    u32 a2 = __hip_atomic_load(&arrive[i0 + 2], __ATOMIC_RELAXED,
                                               __HIP_MEMORY_SCOPE_AGENT);
                    u32 a3 = __hip_atomic_load(&arrive[i0 + 3], __ATOMIC_RELAXED,
                                               __HIP_MEMORY_SCOPE_AGENT);
                    u32 m01 = a0 < a1 ? a0 : a1;
                    u32 m23 = a2 < a3 ? a2 : a3;
                    u32 mn = m01 < m23 ? m01 : m23;
                    if (__all(mn >= epoch)) break;
                    __builtin_amdgcn_s_sleep(2);
                }
                asm volatile("" ::: "memory");   // compiler barrier (no HW fence)
            }
        }
        __syncthreads();   // release other waves into next step
    }
    if (tid < 64) c_out[ub * HIDDEN + j0 + ujj] = creg;
}

// ---------------- init & tails ----------------
__global__ void init_state(const float* __restrict__ h0, const float* __restrict__ c0,
                           float* __restrict__ c_ws, float* __restrict__ ht0,
                           float* __restrict__ ht1, u32* __restrict__ arrive) {
    int gid = blockIdx.x * 256 + threadIdx.x;  // 32768
    if (gid < 256) arrive[gid] = 0;
    c_ws[gid] = c0[gid];
    int l = gid >> 14, b = (gid >> 10) & 15, j = gid & 1023;
    float h = h0[gid];
    float* htp = l ? ht1 : ht0;
    htp[j * BATCH + b] = h;
}

__global__ void write_tails(const float* __restrict__ Hseq0, const float* __restrict__ Hseq1,
                            const float* __restrict__ c_ws, float* __restrict__ out) {
    int gid = blockIdx.x * 256 + threadIdx.x;  // 32768
    int l = gid >> 14, b = (gid >> 10) & 15, j = gid & 1023;
    const float* H = l ? Hseq1 : Hseq0;
    out[LOGITS_SZ + gid] = H[(size_t)((SEQ - 1) * BATCH + b) * HIDDEN + j];
    out[LOGITS_SZ + 32768 + gid] = c_ws[gid];
}

// ---------------- launch ----------------
extern "C" void kernel_launch(void* const* d_in, const int* in_sizes, int n_in,
                              void* d_out, int out_size, void* d_ws, size_t ws_size,
                              hipStream_t stream) {
    const int* x = (const int*)d_in[0];
    const float* h0 = (const float*)d_in[1];
    const float* c0 = (const float*)d_in[2];
    const float* emb = (const float*)d_in[3];
    const float* W_ih0 = (const float*)d_in[4];
    const float* W_hh0 = (const float*)d_in[5];
    const float* b_ih0 = (const float*)d_in[6];
    const float* b_hh0 = (const float*)d_in[7];
    const float* W_ih1 = (const float*)d_in[8];
    const float* W_hh1 = (const float*)d_in[9];
    const float* b_ih1 = (const float*)d_in[10];
    const float* b_hh1 = (const float*)d_in[11];
    const float* fc_W = (const float*)d_in[12];
    const float* fc_b = (const float*)d_in[13];
    float* out = (float*)d_out;
    float* ws = (float*)d_ws;

    // workspace layout (float offsets)
    const size_t OFF_WT0 = 0;                                  // scratch h buffer
    const size_t OFF_WT1 = OFF_WT0 + (size_t)GATES * HIDDEN;   // barrier slots
    const size_t OFF_X0 = OFF_WT1 + (size_t)GATES * HIDDEN;    // 4096*512 (reused: Hseq1 bf16)
    const size_t OFF_G = OFF_X0 + (size_t)MROWS * EMBED;       // 4096*4096 (reused: fc_W bf16)
    const size_t OFF_H0S = OFF_G + (size_t)MROWS * GATES;
    const size_t OFF_H1S = OFF_H0S + (size_t)MROWS * HIDDEN;
    const size_t OFF_PARTS = OFF_H1S + (size_t)MROWS * HIDDEN;
    const size_t OFF_C = OFF_PARTS + (size_t)8 * BATCH * GATES;
    const size_t OFF_HT0 = OFF_C + 2 * BATCH * HIDDEN;
    const size_t OFF_HT1 = OFF_HT0 + (size_t)HIDDEN * BATCH;

    u32* arrive = (u32*)(ws + OFF_WT1);

    init_state<<<128, 256, 0, stream>>>(h0, c0, ws + OFF_C, ws + OFF_HT0,
                                        ws + OFF_HT1, arrive);
    embed_kernel<<<MROWS, 128, 0, stream>>>(x, emb, ws + OFF_X0);

    // layer 0: input projection for all timesteps, then persistent recurrence
    gemm_bt<<<dim3(GATES / 128, MROWS / 128), 256, 0, stream>>>(
        ws + OFF_X0, W_ih0, b_ih0, b_hh0, ws + OFF_G, MROWS, GATES, EMBED, 0);
    {
        const float* Gp = ws + OFF_G;
        const float* ci = c0;
        float* co = ws + OFF_C;
        float* hs = ws + OFF_H0S;
        float* hbA = ws + OFF_HT0;
        float* hbB = ws + OFF_WT0;
        int ebase = 0;
        void* args[] = {(void*)&W_hh0, (void*)&Gp, (void*)&ci, (void*)&co,
                        (void*)&hs, (void*)&hbA, (void*)&hbB, (void*)&arrive,
                        (void*)&ebase};
        hipLaunchCooperativeKernel((void*)lstm_layer_persistent, dim3(RBLOCKS),
                                   dim3(RTHREADS), args, 0, stream);
    }

    // layer 1
    gemm_bt<<<dim3(GATES / 128, MROWS / 128), 256, 0, stream>>>(
        ws + OFF_H0S, W_ih1, b_ih1, b_hh1, ws + OFF_G, MROWS, GATES, HIDDEN, 0);
    {
        const float* Gp = ws + OFF_G;
        const float* ci = c0 + BATCH * HIDDEN;
        float* co = ws + OFF_C + BATCH * HIDDEN;
        float* hs = ws + OFF_H1S;
        float* hbA = ws + OFF_HT1;
        float* hbB = ws + OFF_WT0;
        int ebase = SEQ;
        void* args[] = {(void*)&W_hh1, (void*)&Gp, (void*)&ci, (void*)&co,
                        (void*)&hs, (void*)&hbA, (void*)&hbB, (void*)&arrive,
                        (void*)&ebase};
        hipLaunchCooperativeKernel((void*)lstm_layer_persistent, dim3(RBLOCKS),
                                   dim3(RTHREADS), args, 0, stream);
    }

    // FC via bf16 MFMA: convert operands (G and X0 are dead now), then MFMA GEMM.
    f32_to_bf16_kernel<<<4096, 256, 0, stream>>>(fc_W, (u16*)(ws + OFF_G), VOCAB * HIDDEN / 8);
    f32_to_bf16_kernel<<<2048, 256, 0, stream>>>(ws + OFF_H1S, (u16*)(ws + OFF_X0),
                                                 MROWS * HIDDEN / 8);
    fc_mfma<<<dim3(VOCAB / 128, MROWS / 128), 256, 0, stream>>>(
        (const u16*)(ws + OFF_X0), (const u16*)(ws + OFF_G), fc_b, out);

    write_tails<<<128, 256, 0, stream>>>(ws + OFF_H0S, ws + OFF_H1S, ws + OFF_C, out);
}

// Round 5
// 5996.092 us; speedup vs baseline: 6.4603x; 1.0252x over previous
//
#include <hip/hip_runtime.h>
#include <hip/hip_bf16.h>
#include <cmath>

// Problem constants
#define BATCH 16
#define SEQ 256
#define EMBED 512
#define HIDDEN 1024
#define GATES 4096       // 4*HIDDEN
#define VOCAB 32000
#define MROWS 4096       // BATCH*SEQ
#define LOGITS_SZ 131072000  // 16*256*32000

#define RBLOCKS 256
#define RTHREADS 512

typedef unsigned int u32;
typedef unsigned short u16;
typedef unsigned long long u64;
typedef __attribute__((ext_vector_type(8))) short bf16x8;
typedef __attribute__((ext_vector_type(4))) float f32x4;

#define AS1 __attribute__((address_space(1)))
#define AS3 __attribute__((address_space(3)))

// ---------------- helpers ----------------
__device__ __forceinline__ u32 f2bf(float f) {          // RNE fp32->bf16 (bits)
    u32 u = __float_as_uint(f);
    return (u + 0x7fffu + ((u >> 16) & 1u)) >> 16;
}
__device__ __forceinline__ float bf2f(u32 b) { return __uint_as_float(b << 16); }

// ---------------- embedding gather ----------------
__global__ void embed_kernel(const int* __restrict__ x, const float* __restrict__ emb,
                             float* __restrict__ X0) {
    int r = blockIdx.x;            // r = s*16 + b
    int s = r >> 4, b = r & 15;
    int tok = x[b * SEQ + s];
    const float4* src = (const float4*)(emb + (size_t)tok * EMBED);
    float4* dst = (float4*)(X0 + (size_t)r * EMBED);
    for (int i = threadIdx.x; i < EMBED / 4; i += blockDim.x) dst[i] = src[i];
}

// ---------------- fp32 GEMM: C[M,N] = A[M,K] @ B[N,K]^T + b1 + b2 ----------------
__global__ __launch_bounds__(256) void gemm_bt(
    const float* __restrict__ A, const float* __restrict__ B,
    const float* __restrict__ b1, const float* __restrict__ b2,
    float* __restrict__ C, int M, int N, int K, int perm) {
    __shared__ float As[8][128];
    __shared__ float Bs[8][128];
    int tid = threadIdx.x;
    int bm = blockIdx.y, bn = blockIdx.x;
    int arow = tid >> 1;              // 0..127
    int ak4 = (tid & 1) * 4;          // 0 or 4
    const float* Ag = A + (size_t)(bm * 128 + arow) * K + ak4;
    const float* Bg = B + (size_t)(bn * 128 + arow) * K + ak4;
    int tx = tid & 15, ty = tid >> 4;

    float acc[8][8];
#pragma unroll
    for (int i = 0; i < 8; i++)
#pragma unroll
        for (int j = 0; j < 8; j++) acc[i][j] = 0.f;

    for (int k0 = 0; k0 < K; k0 += 8) {
        float4 a4 = *(const float4*)(Ag + k0);
        float4 b4 = *(const float4*)(Bg + k0);
        __syncthreads();
        As[ak4 + 0][arow] = a4.x; As[ak4 + 1][arow] = a4.y;
        As[ak4 + 2][arow] = a4.z; As[ak4 + 3][arow] = a4.w;
        Bs[ak4 + 0][arow] = b4.x; Bs[ak4 + 1][arow] = b4.y;
        Bs[ak4 + 2][arow] = b4.z; Bs[ak4 + 3][arow] = b4.w;
        __syncthreads();
#pragma unroll
        for (int k = 0; k < 8; k++) {
            float av[8], bv[8];
            *(float4*)(av + 0) = *(const float4*)&As[k][ty * 8 + 0];
            *(float4*)(av + 4) = *(const float4*)&As[k][ty * 8 + 4];
            *(float4*)(bv + 0) = *(const float4*)&Bs[k][tx * 8 + 0];
            *(float4*)(bv + 4) = *(const float4*)&Bs[k][tx * 8 + 4];
#pragma unroll
            for (int i = 0; i < 8; i++)
#pragma unroll
                for (int j = 0; j < 8; j++) acc[i][j] += av[i] * bv[j];
        }
    }

#pragma unroll
    for (int i = 0; i < 8; i++) {
        int r = bm * 128 + ty * 8 + i;
        int orow = perm ? ((r & 15) * SEQ + (r >> 4)) : r;
#pragma unroll
        for (int j = 0; j < 8; j += 4) {
            int c = bn * 128 + tx * 8 + j;
            float4 v;
            float bb0 = (b1 ? b1[c + 0] : 0.f) + (b2 ? b2[c + 0] : 0.f);
            float bb1 = (b1 ? b1[c + 1] : 0.f) + (b2 ? b2[c + 1] : 0.f);
            float bb2 = (b1 ? b1[c + 2] : 0.f) + (b2 ? b2[c + 2] : 0.f);
            float bb3 = (b1 ? b1[c + 3] : 0.f) + (b2 ? b2[c + 3] : 0.f);
            v.x = acc[i][j + 0] + bb0;
            v.y = acc[i][j + 1] + bb1;
            v.z = acc[i][j + 2] + bb2;
            v.w = acc[i][j + 3] + bb3;
            *(float4*)&C[(size_t)orow * N + c] = v;
        }
    }
}

// ---------------- fp32 -> bf16 conversion kernel ----------------
__global__ __launch_bounds__(256) void f32_to_bf16_kernel(
    const float* __restrict__ in, u16* __restrict__ out, int n8) {
    for (int i = blockIdx.x * 256 + threadIdx.x; i < n8; i += gridDim.x * 256) {
        float4 a = ((const float4*)in)[2 * (size_t)i + 0];
        float4 b = ((const float4*)in)[2 * (size_t)i + 1];
        uint4 o;
        o.x = f2bf(a.x) | (f2bf(a.y) << 16);
        o.y = f2bf(a.z) | (f2bf(a.w) << 16);
        o.z = f2bf(b.x) | (f2bf(b.y) << 16);
        o.w = f2bf(b.z) | (f2bf(b.w) << 16);
        ((uint4*)out)[i] = o;
    }
}

// ---------------- bf16 MFMA FC GEMM ----------------
__global__ __launch_bounds__(256) void fc_mfma(
    const u16* __restrict__ Abf,   // [MROWS][1024] bf16
    const u16* __restrict__ Bbf,   // [VOCAB][1024] bf16
    const float* __restrict__ bias,
    float* __restrict__ C) {
    const int K = HIDDEN;          // 1024
    const int N = VOCAB;
    __shared__ char smem[16384];   // As 8KB + Bs 8KB
    char* As = smem;
    char* Bs = smem + 8192;

    int tid = threadIdx.x;
    int w = tid >> 6, l = tid & 63;
    int bn = blockIdx.x, bm = blockIdx.y;
    int wr = w >> 1, wc = w & 1;
    int lr = l & 15, lk = l >> 4;

    f32x4 acc[4][4];
#pragma unroll
    for (int m = 0; m < 4; m++)
#pragma unroll
        for (int n = 0; n < 4; n++) acc[m][n] = {0.f, 0.f, 0.f, 0.f};

    int srow = tid >> 2, skc = (tid & 3) * 8;
    const u16* ga0 = Abf + (size_t)(bm * 128 + srow) * K + skc;
    const u16* ga1 = Abf + (size_t)(bm * 128 + 64 + srow) * K + skc;
    const u16* gb0 = Bbf + (size_t)(bn * 128 + srow) * K + skc;
    const u16* gb1 = Bbf + (size_t)(bn * 128 + 64 + srow) * K + skc;
    char* la0 = As + w * 1024;
    char* la1 = As + 4096 + w * 1024;
    char* lb0 = Bs + w * 1024;
    char* lb1 = Bs + 4096 + w * 1024;

    int afo[4], bfo[4];
#pragma unroll
    for (int m = 0; m < 4; m++) afo[m] = (wr * 64 + m * 16 + lr) * 64 + lk * 16;
#pragma unroll
    for (int n = 0; n < 4; n++) bfo[n] = (wc * 64 + n * 16 + lr) * 64 + lk * 16;

    for (int k0 = 0; k0 < K; k0 += 32) {
        __syncthreads();
        __builtin_amdgcn_global_load_lds((const AS1 u32*)(const void*)(ga0 + k0),
                                         (AS3 u32*)(void*)la0, 16, 0, 0);
        __builtin_amdgcn_global_load_lds((const AS1 u32*)(const void*)(ga1 + k0),
                                         (AS3 u32*)(void*)la1, 16, 0, 0);
        __builtin_amdgcn_global_load_lds((const AS1 u32*)(const void*)(gb0 + k0),
                                         (AS3 u32*)(void*)lb0, 16, 0, 0);
        __builtin_amdgcn_global_load_lds((const AS1 u32*)(const void*)(gb1 + k0),
                                         (AS3 u32*)(void*)lb1, 16, 0, 0);
        __syncthreads();

        bf16x8 af[4], bfr[4];
#pragma unroll
        for (int m = 0; m < 4; m++) af[m] = *(const bf16x8*)(As + afo[m]);
#pragma unroll
        for (int n = 0; n < 4; n++) bfr[n] = *(const bf16x8*)(Bs + bfo[n]);
#pragma unroll
        for (int m = 0; m < 4; m++)
#pragma unroll
            for (int n = 0; n < 4; n++)
                acc[m][n] = __builtin_amdgcn_mfma_f32_16x16x32_bf16(
                    af[m], bfr[n], acc[m][n], 0, 0, 0);
    }

    int rbase = bm * 128 + wr * 64 + lk * 4;
    int cbase = bn * 128 + wc * 64 + lr;
#pragma unroll
    for (int m = 0; m < 4; m++) {
#pragma unroll
        for (int n = 0; n < 4; n++) {
            int c = cbase + n * 16;
            float bb = bias[c];
#pragma unroll
            for (int j = 0; j < 4; j++) {
                int r = rbase + m * 16 + j;
                int orow = (r & 15) * SEQ + (r >> 4);   // [B,S,V] layout
                C[(size_t)orow * N + c] = acc[m][n][j] + bb;
            }
        }
    }
}

// ---------------- persistent LSTM layer, split-precision MFMA recurrence ------
// 256 blocks x 512 threads. Block owns 4 hidden units = 16 gate cols.
// Per step: one 16x16x1024 GEMM as 96 MFMAs (Whi*hhi + Wlo*hhi + Whi*hlo) in
// wave 0. W hi/lo staged once in LDS; h exchanged as bf16 hi/lo via
// relaxed-AGENT atomics; arrive-flag barrier (R4-proven).
// h-exchange buffer hx (u16): [parity][hi16K|lo16K] ; hT layout [b][1024 k].
__global__ __launch_bounds__(RTHREADS) void lstm_layer_persistent(
    const float* __restrict__ Whh,    // [4096][1024] row-major
    const float* __restrict__ G,      // [4096][4096] rows t*16+b (x-proj + biases)
    const float* __restrict__ c_init, // [16][1024]
    float* __restrict__ c_out,        // [16][1024]
    float* __restrict__ Hseq,         // [4096][1024] rows t*16+b
    u16* __restrict__ hx,             // [2 parity][2 hi/lo][16][1024] bf16
    u32* __restrict__ arrive,         // [256] monotone epoch slots
    int ebase) {
    __shared__ __align__(16) char lds[132352];
    char* Wlhi = lds;                 // 32 KB, swizzled [c][k]
    char* Wllo = lds + 32768;
    char* Hlhi = lds + 65536;         // 32 KB, swizzled [b][k]
    char* Hllo = lds + 98304;
    float* Gl = (float*)(lds + 131072);  // [16][17] gate grid (1088 B)

    const int tid = threadIdx.x;
    const int bid = blockIdx.x;
    const int j0 = bid * 4;                  // 4 hidden units per block
    const int l = tid & 63;
    const int ub = tid >> 2, ujj = tid & 3;  // update mapping for tid<64

    // ---- one-time: stage W_hh slice as bf16 hi/lo into LDS (swizzled) ----
#pragma unroll
    for (int i = 0; i < 4; i++) {
        int q = i * 512 + tid;            // 16B chunk id 0..2047
        int row = q >> 7, cin = q & 127;  // row = c (0..15), chunk within row
        int nrow = (row >> 2) * HIDDEN + j0 + (row & 3);
        const float* src = Whh + (size_t)nrow * HIDDEN + cin * 8;
        int dst = row * 2048 + ((cin ^ (row & 7)) << 4);
        u32 hw[4], lw[4];
#pragma unroll
        for (int e = 0; e < 4; e++) {
            float x0 = src[2 * e], x1 = src[2 * e + 1];
            u32 h0 = f2bf(x0), h1 = f2bf(x1);
            hw[e] = h0 | (h1 << 16);
            lw[e] = f2bf(x0 - bf2f(h0)) | (f2bf(x1 - bf2f(h1)) << 16);
        }
        *(uint4*)(Wlhi + dst) = make_uint4(hw[0], hw[1], hw[2], hw[3]);
        *(uint4*)(Wllo + dst) = make_uint4(lw[0], lw[1], lw[2], lw[3]);
    }

    float creg = 0.f;
    if (tid < 64) creg = c_init[ub * HIDDEN + j0 + ujj];

    for (int t = 0; t < SEQ; t++) {
        // ---- stage h_t (bf16 hi/lo) into LDS, swizzled ----
        {
            const u16* shp = hx + (t & 1) * 32768;
            const u64* shi = (const u64*)shp;
            const u64* slo = (const u64*)(shp + 16384);
            u64 th[8], tl[8];
#pragma unroll
            for (int i = 0; i < 4; i++) {
                int q = i * 512 + tid;
                th[2 * i + 0] = __hip_atomic_load(shi + 2 * q + 0, __ATOMIC_RELAXED,
                                                  __HIP_MEMORY_SCOPE_AGENT);
                th[2 * i + 1] = __hip_atomic_load(shi + 2 * q + 1, __ATOMIC_RELAXED,
                                                  __HIP_MEMORY_SCOPE_AGENT);
                tl[2 * i + 0] = __hip_atomic_load(slo + 2 * q + 0, __ATOMIC_RELAXED,
                                                  __HIP_MEMORY_SCOPE_AGENT);
                tl[2 * i + 1] = __hip_atomic_load(slo + 2 * q + 1, __ATOMIC_RELAXED,
                                                  __HIP_MEMORY_SCOPE_AGENT);
            }
#pragma unroll
            for (int i = 0; i < 4; i++) {
                int q = i * 512 + tid;
                int row = q >> 7, cin = q & 127;
                int dst = row * 2048 + ((cin ^ (row & 7)) << 4);
                *(u64*)(Hlhi + dst + 0) = th[2 * i + 0];
                *(u64*)(Hlhi + dst + 8) = th[2 * i + 1];
                *(u64*)(Hllo + dst + 0) = tl[2 * i + 0];
                *(u64*)(Hllo + dst + 8) = tl[2 * i + 1];
            }
        }
        __syncthreads();

        if (tid < 64) {
            // G gather (float4/lane), overlaps the MFMA phase
            const float4 g4 = *(const float4*)(
                G + ((size_t)(t * BATCH + (l & 15))) * GATES + (l >> 4) * HIDDEN + j0);

            const int row2048 = (l & 15) * 2048;
            const int xr = l & 7;        // (l&15)&7
            const int hi4 = l >> 4;
            f32x4 a0a = {0.f,0.f,0.f,0.f}, a0b = {0.f,0.f,0.f,0.f};
            f32x4 a1a = {0.f,0.f,0.f,0.f}, a1b = {0.f,0.f,0.f,0.f};
            f32x4 a2a = {0.f,0.f,0.f,0.f}, a2b = {0.f,0.f,0.f,0.f};
#pragma unroll
            for (int s = 0; s < 32; s++) {
                int off = row2048 + ((((s << 2) + hi4) ^ xr) << 4);
                bf16x8 ah = *(const bf16x8*)(Wlhi + off);
                bf16x8 al = *(const bf16x8*)(Wllo + off);
                bf16x8 bh = *(const bf16x8*)(Hlhi + off);
                bf16x8 bl = *(const bf16x8*)(Hllo + off);
                if (s & 1) {
                    a0b = __builtin_amdgcn_mfma_f32_16x16x32_bf16(ah, bh, a0b, 0, 0, 0);
                    a1b = __builtin_amdgcn_mfma_f32_16x16x32_bf16(al, bh, a1b, 0, 0, 0);
                    a2b = __builtin_amdgcn_mfma_f32_16x16x32_bf16(ah, bl, a2b, 0, 0, 0);
                } else {
                    a0a = __builtin_amdgcn_mfma_f32_16x16x32_bf16(ah, bh, a0a, 0, 0, 0);
                    a1a = __builtin_amdgcn_mfma_f32_16x16x32_bf16(al, bh, a1a, 0, 0, 0);
                    a2a = __builtin_amdgcn_mfma_f32_16x16x32_bf16(ah, bl, a2a, 0, 0, 0);
                }
            }
            f32x4 vs = a0a + a0b + a1a + a1b + a2a + a2b;

            // gate exchange: D layout row=(l>>4)*4+j -> gate-col c, col=l&15 -> b
            Gl[((hi4 << 2) + 0) * 17 + (l & 15)] = vs[0] + g4.x;
            Gl[((hi4 << 2) + 1) * 17 + (l & 15)] = vs[1] + g4.y;
            Gl[((hi4 << 2) + 2) * 17 + (l & 15)] = vs[2] + g4.z;
            Gl[((hi4 << 2) + 3) * 17 + (l & 15)] = vs[3] + g4.w;
            asm volatile("s_waitcnt lgkmcnt(0)" ::: "memory");
            const float pi = Gl[(0 + ujj) * 17 + ub];
            const float pf = Gl[(4 + ujj) * 17 + ub];
            const float pg = Gl[(8 + ujj) * 17 + ub];
            const float po = Gl[(12 + ujj) * 17 + ub];

            const float ig = 1.f / (1.f + __expf(-pi));
            const float fg = 1.f / (1.f + __expf(-pf));
            const float gt = tanhf(pg);
            const float og = 1.f / (1.f + __expf(-po));
            creg = fg * creg + ig * gt;
            const float hv = og * tanhf(creg);
            Hseq[((size_t)(t * BATCH + ub)) * HIDDEN + j0 + ujj] = hv;

            // pack 4-unit quads (batch = l&15) via shuffle; 16 lanes store u64 hi/lo
            float x0 = __shfl(hv, (l & 15) * 4 + 0);
            float x1 = __shfl(hv, (l & 15) * 4 + 1);
            float x2 = __shfl(hv, (l & 15) * 4 + 2);
            float x3 = __shfl(hv, (l & 15) * 4 + 3);
            u32 h0 = f2bf(x0), h1 = f2bf(x1), h2 = f2bf(x2), h3 = f2bf(x3);
            u64 hq = (u64)(h0 | (h1 << 16)) | ((u64)(h2 | (h3 << 16)) << 32);
            u32 l0 = f2bf(x0 - bf2f(h0)), l1 = f2bf(x1 - bf2f(h1));
            u32 l2 = f2bf(x2 - bf2f(h2)), l3 = f2bf(x3 - bf2f(h3));
            u64 lq = (u64)(l0 | (l1 << 16)) | ((u64)(l2 | (l3 << 16)) << 32);
            u16* dhp = hx + ((t & 1) ^ 1) * 32768;
            if (l < 16) {
                __hip_atomic_store((u64*)dhp + ((l * 1024 + j0) >> 2), hq,
                                   __ATOMIC_RELAXED, __HIP_MEMORY_SCOPE_AGENT);
                __hip_atomic_store((u64*)(dhp + 16384) + ((l * 1024 + j0) >> 2), lq,
                                   __ATOMIC_RELAXED, __HIP_MEMORY_SCOPE_AGENT);
            }

            if (t < SEQ - 1) {
                const u32 epoch = (u32)(ebase + t + 1);
                asm volatile("s_waitcnt vmcnt(0)" ::: "memory");
                if (tid == 0)
                    __hip_atomic_store(&arrive[bid], epoch, __ATOMIC_RELAXED,
                                       __HIP_MEMORY_SCOPE_AGENT);
                const int i0 = l * 4;
                for (;;) {
                    u32 a0 = __hip_atomic_load(&arrive[i0 + 0], __ATOMIC_RELAXED,
                                               __HIP_MEMORY_SCOPE_AGENT);
                    u32 a1 = __hip_atomic_load(&arrive[i0 + 1], __ATOMIC_RELAXED,
                                               __HIP_MEMORY_SCOPE_AGENT);
                    u32 a2 = __hip_atomic_load(&arrive[i0 + 2], __ATOMIC_RELAXED,
                                               __HIP_MEMORY_SCOPE_AGENT);
                    u32 a3 = __hip_atomic_load(&arrive[i0 + 3], __ATOMIC_RELAXED,
                                               __HIP_MEMORY_SCOPE_AGENT);
                    u32 m01 = a0 < a1 ? a0 : a1;
                    u32 m23 = a2 < a3 ? a2 : a3;
                    u32 mn = m01 < m23 ? m01 : m23;
                    if (__all(mn >= epoch)) break;
                    __builtin_amdgcn_s_sleep(2);
                }
                asm volatile("" ::: "memory");   // compiler barrier only
            }
        }
        __syncthreads();   // release all waves into next step
    }
    if (tid < 64) c_out[ub * HIDDEN + j0 + ujj] = creg;
}

// ---------------- init & tails ----------------
__global__ void init_state(const float* __restrict__ h0, const float* __restrict__ c0,
                           float* __restrict__ c_ws, u16* __restrict__ hx,
                           u32* __restrict__ arrive) {
    int gid = blockIdx.x * 256 + threadIdx.x;  // 32768 = 2*16*1024
    if (gid < 256) arrive[gid] = 0;
    c_ws[gid] = c0[gid];
    int layer = gid >> 14, b = (gid >> 10) & 15, j = gid & 1023;
    float h = h0[gid];
    u32 hb = f2bf(h);
    u32 lb = f2bf(h - bf2f(hb));
    u16* base = hx + layer * 65536;          // per-layer region, parity 0
    base[b * 1024 + j] = (u16)hb;
    base[16384 + b * 1024 + j] = (u16)lb;
}

__global__ void write_tails(const float* __restrict__ Hseq0, const float* __restrict__ Hseq1,
                            const float* __restrict__ c_ws, float* __restrict__ out) {
    int gid = blockIdx.x * 256 + threadIdx.x;  // 32768
    int l = gid >> 14, b = (gid >> 10) & 15, j = gid & 1023;
    const float* H = l ? Hseq1 : Hseq0;
    out[LOGITS_SZ + gid] = H[(size_t)((SEQ - 1) * BATCH + b) * HIDDEN + j];
    out[LOGITS_SZ + 32768 + gid] = c_ws[gid];
}

// ---------------- launch ----------------
extern "C" void kernel_launch(void* const* d_in, const int* in_sizes, int n_in,
                              void* d_out, int out_size, void* d_ws, size_t ws_size,
                              hipStream_t stream) {
    const int* x = (const int*)d_in[0];
    const float* h0 = (const float*)d_in[1];
    const float* c0 = (const float*)d_in[2];
    const float* emb = (const float*)d_in[3];
    const float* W_ih0 = (const float*)d_in[4];
    const float* W_hh0 = (const float*)d_in[5];
    const float* b_ih0 = (const float*)d_in[6];
    const float* b_hh0 = (const float*)d_in[7];
    const float* W_ih1 = (const float*)d_in[8];
    const float* W_hh1 = (const float*)d_in[9];
    const float* b_ih1 = (const float*)d_in[10];
    const float* b_hh1 = (const float*)d_in[11];
    const float* fc_W = (const float*)d_in[12];
    const float* fc_b = (const float*)d_in[13];
    float* out = (float*)d_out;
    float* ws = (float*)d_ws;

    // workspace layout (float offsets)
    const size_t OFF_WT0 = 0;                                  // h-exchange (hi/lo, 2 layers)
    const size_t OFF_WT1 = OFF_WT0 + (size_t)GATES * HIDDEN;   // barrier slots
    const size_t OFF_X0 = OFF_WT1 + (size_t)GATES * HIDDEN;    // 4096*512 (reused: Hseq1 bf16)
    const size_t OFF_G = OFF_X0 + (size_t)MROWS * EMBED;       // 4096*4096 (reused: fc_W bf16)
    const size_t OFF_H0S = OFF_G + (size_t)MROWS * GATES;
    const size_t OFF_H1S = OFF_H0S + (size_t)MROWS * HIDDEN;
    const size_t OFF_PARTS = OFF_H1S + (size_t)MROWS * HIDDEN;
    const size_t OFF_C = OFF_PARTS + (size_t)8 * BATCH * GATES;

    u16* hx = (u16*)(ws + OFF_WT0);           // 2 layers x 128 KB
    u32* arrive = (u32*)(ws + OFF_WT1);

    init_state<<<128, 256, 0, stream>>>(h0, c0, ws + OFF_C, hx, arrive);
    embed_kernel<<<MROWS, 128, 0, stream>>>(x, emb, ws + OFF_X0);

    // layer 0: input projection for all timesteps, then persistent recurrence
    gemm_bt<<<dim3(GATES / 128, MROWS / 128), 256, 0, stream>>>(
        ws + OFF_X0, W_ih0, b_ih0, b_hh0, ws + OFF_G, MROWS, GATES, EMBED, 0);
    {
        const float* Gp = ws + OFF_G;
        const float* ci = c0;
        float* co = ws + OFF_C;
        float* hs = ws + OFF_H0S;
        u16* hxl = hx;
        int ebase = 0;
        void* args[] = {(void*)&W_hh0, (void*)&Gp, (void*)&ci, (void*)&co,
                        (void*)&hs, (void*)&hxl, (void*)&arrive, (void*)&ebase};
        hipLaunchCooperativeKernel((void*)lstm_layer_persistent, dim3(RBLOCKS),
                                   dim3(RTHREADS), args, 0, stream);
    }

    // layer 1
    gemm_bt<<<dim3(GATES / 128, MROWS / 128), 256, 0, stream>>>(
        ws + OFF_H0S, W_ih1, b_ih1, b_hh1, ws + OFF_G, MROWS, GATES, HIDDEN, 0);
    {
        const float* Gp = ws + OFF_G;
        const float* ci = c0 + BATCH * HIDDEN;
        float* co = ws + OFF_C + BATCH * HIDDEN;
        float* hs = ws + OFF_H1S;
        u16* hxl = hx + 65536;
        int ebase = SEQ;
        void* args[] = {(void*)&W_hh1, (void*)&Gp, (void*)&ci, (void*)&co,
                        (void*)&hs, (void*)&hxl, (void*)&arrive, (void*)&ebase};
        hipLaunchCooperativeKernel((void*)lstm_layer_persistent, dim3(RBLOCKS),
                                   dim3(RTHREADS), args, 0, stream);
    }

    // FC via bf16 MFMA: convert operands (G and X0 are dead now), then MFMA GEMM.
    f32_to_bf16_kernel<<<4096, 256, 0, stream>>>(fc_W, (u16*)(ws + OFF_G), VOCAB * HIDDEN / 8);
    f32_to_bf16_kernel<<<2048, 256, 0, stream>>>(ws + OFF_H1S, (u16*)(ws + OFF_X0),
                                                 MROWS * HIDDEN / 8);
    fc_mfma<<<dim3(VOCAB / 128, MROWS / 128), 256, 0, stream>>>(
        (const u16*)(ws + OFF_X0), (const u16*)(ws + OFF_G), fc_b, out);

    write_tails<<<128, 256, 0, stream>>>(ws + OFF_H0S, ws + OFF_H1S, ws + OFF_C, out);
}

// Round 6
// 5702.087 us; speedup vs baseline: 6.7934x; 1.0516x over previous
//
#include <hip/hip_runtime.h>
#include <hip/hip_bf16.h>
#include <cmath>

// Problem constants
#define BATCH 16
#define SEQ 256
#define EMBED 512
#define HIDDEN 1024
#define GATES 4096       // 4*HIDDEN
#define VOCAB 32000
#define MROWS 4096       // BATCH*SEQ
#define LOGITS_SZ 131072000  // 16*256*32000

#define RBLOCKS 256
#define RT 256           // 4 waves per block

typedef unsigned int u32;
typedef unsigned short u16;
typedef unsigned long long u64;
typedef __attribute__((ext_vector_type(8))) short bf16x8;
typedef __attribute__((ext_vector_type(4))) float f32x4;

#define AS1 __attribute__((address_space(1)))
#define AS3 __attribute__((address_space(3)))

// ---------------- helpers ----------------
__device__ __forceinline__ u32 f2bf(float f) {          // RNE fp32->bf16 (bits)
    u32 u = __float_as_uint(f);
    return (u + 0x7fffu + ((u >> 16) & 1u)) >> 16;
}
__device__ __forceinline__ float bf2f(u32 b) { return __uint_as_float(b << 16); }

// ---------------- embedding gather ----------------
__global__ void embed_kernel(const int* __restrict__ x, const float* __restrict__ emb,
                             float* __restrict__ X0) {
    int r = blockIdx.x;            // r = s*16 + b
    int s = r >> 4, b = r & 15;
    int tok = x[b * SEQ + s];
    const float4* src = (const float4*)(emb + (size_t)tok * EMBED);
    float4* dst = (float4*)(X0 + (size_t)r * EMBED);
    for (int i = threadIdx.x; i < EMBED / 4; i += blockDim.x) dst[i] = src[i];
}

// ---------------- fp32 GEMM: C[M,N] = A[M,K] @ B[N,K]^T + b1 + b2 ----------------
__global__ __launch_bounds__(256) void gemm_bt(
    const float* __restrict__ A, const float* __restrict__ B,
    const float* __restrict__ b1, const float* __restrict__ b2,
    float* __restrict__ C, int M, int N, int K, int perm) {
    __shared__ float As[8][128];
    __shared__ float Bs[8][128];
    int tid = threadIdx.x;
    int bm = blockIdx.y, bn = blockIdx.x;
    int arow = tid >> 1;              // 0..127
    int ak4 = (tid & 1) * 4;          // 0 or 4
    const float* Ag = A + (size_t)(bm * 128 + arow) * K + ak4;
    const float* Bg = B + (size_t)(bn * 128 + arow) * K + ak4;
    int tx = tid & 15, ty = tid >> 4;

    float acc[8][8];
#pragma unroll
    for (int i = 0; i < 8; i++)
#pragma unroll
        for (int j = 0; j < 8; j++) acc[i][j] = 0.f;

    for (int k0 = 0; k0 < K; k0 += 8) {
        float4 a4 = *(const float4*)(Ag + k0);
        float4 b4 = *(const float4*)(Bg + k0);
        __syncthreads();
        As[ak4 + 0][arow] = a4.x; As[ak4 + 1][arow] = a4.y;
        As[ak4 + 2][arow] = a4.z; As[ak4 + 3][arow] = a4.w;
        Bs[ak4 + 0][arow] = b4.x; Bs[ak4 + 1][arow] = b4.y;
        Bs[ak4 + 2][arow] = b4.z; Bs[ak4 + 3][arow] = b4.w;
        __syncthreads();
#pragma unroll
        for (int k = 0; k < 8; k++) {
            float av[8], bv[8];
            *(float4*)(av + 0) = *(const float4*)&As[k][ty * 8 + 0];
            *(float4*)(av + 4) = *(const float4*)&As[k][ty * 8 + 4];
            *(float4*)(bv + 0) = *(const float4*)&Bs[k][tx * 8 + 0];
            *(float4*)(bv + 4) = *(const float4*)&Bs[k][tx * 8 + 4];
#pragma unroll
            for (int i = 0; i < 8; i++)
#pragma unroll
                for (int j = 0; j < 8; j++) acc[i][j] += av[i] * bv[j];
        }
    }

#pragma unroll
    for (int i = 0; i < 8; i++) {
        int r = bm * 128 + ty * 8 + i;
        int orow = perm ? ((r & 15) * SEQ + (r >> 4)) : r;
#pragma unroll
        for (int j = 0; j < 8; j += 4) {
            int c = bn * 128 + tx * 8 + j;
            float4 v;
            float bb0 = (b1 ? b1[c + 0] : 0.f) + (b2 ? b2[c + 0] : 0.f);
            float bb1 = (b1 ? b1[c + 1] : 0.f) + (b2 ? b2[c + 1] : 0.f);
            float bb2 = (b1 ? b1[c + 2] : 0.f) + (b2 ? b2[c + 2] : 0.f);
            float bb3 = (b1 ? b1[c + 3] : 0.f) + (b2 ? b2[c + 3] : 0.f);
            v.x = acc[i][j + 0] + bb0;
            v.y = acc[i][j + 1] + bb1;
            v.z = acc[i][j + 2] + bb2;
            v.w = acc[i][j + 3] + bb3;
            *(float4*)&C[(size_t)orow * N + c] = v;
        }
    }
}

// ---------------- fp32 -> bf16 conversion kernel ----------------
__global__ __launch_bounds__(256) void f32_to_bf16_kernel(
    const float* __restrict__ in, u16* __restrict__ out, int n8) {
    for (int i = blockIdx.x * 256 + threadIdx.x; i < n8; i += gridDim.x * 256) {
        float4 a = ((const float4*)in)[2 * (size_t)i + 0];
        float4 b = ((const float4*)in)[2 * (size_t)i + 1];
        uint4 o;
        o.x = f2bf(a.x) | (f2bf(a.y) << 16);
        o.y = f2bf(a.z) | (f2bf(a.w) << 16);
        o.z = f2bf(b.x) | (f2bf(b.y) << 16);
        o.w = f2bf(b.z) | (f2bf(b.w) << 16);
        ((uint4*)out)[i] = o;
    }
}

// ---------------- bf16 MFMA FC GEMM ----------------
__global__ __launch_bounds__(256) void fc_mfma(
    const u16* __restrict__ Abf,   // [MROWS][1024] bf16
    const u16* __restrict__ Bbf,   // [VOCAB][1024] bf16
    const float* __restrict__ bias,
    float* __restrict__ C) {
    const int K = HIDDEN;          // 1024
    const int N = VOCAB;
    __shared__ char smem[16384];   // As 8KB + Bs 8KB
    char* As = smem;
    char* Bs = smem + 8192;

    int tid = threadIdx.x;
    int w = tid >> 6, l = tid & 63;
    int bn = blockIdx.x, bm = blockIdx.y;
    int wr = w >> 1, wc = w & 1;
    int lr = l & 15, lk = l >> 4;

    f32x4 acc[4][4];
#pragma unroll
    for (int m = 0; m < 4; m++)
#pragma unroll
        for (int n = 0; n < 4; n++) acc[m][n] = {0.f, 0.f, 0.f, 0.f};

    int srow = tid >> 2, skc = (tid & 3) * 8;
    const u16* ga0 = Abf + (size_t)(bm * 128 + srow) * K + skc;
    const u16* ga1 = Abf + (size_t)(bm * 128 + 64 + srow) * K + skc;
    const u16* gb0 = Bbf + (size_t)(bn * 128 + srow) * K + skc;
    const u16* gb1 = Bbf + (size_t)(bn * 128 + 64 + srow) * K + skc;
    char* la0 = As + w * 1024;
    char* la1 = As + 4096 + w * 1024;
    char* lb0 = Bs + w * 1024;
    char* lb1 = Bs + 4096 + w * 1024;

    int afo[4], bfo[4];
#pragma unroll
    for (int m = 0; m < 4; m++) afo[m] = (wr * 64 + m * 16 + lr) * 64 + lk * 16;
#pragma unroll
    for (int n = 0; n < 4; n++) bfo[n] = (wc * 64 + n * 16 + lr) * 64 + lk * 16;

    for (int k0 = 0; k0 < K; k0 += 32) {
        __syncthreads();
        __builtin_amdgcn_global_load_lds((const AS1 u32*)(const void*)(ga0 + k0),
                                         (AS3 u32*)(void*)la0, 16, 0, 0);
        __builtin_amdgcn_global_load_lds((const AS1 u32*)(const void*)(ga1 + k0),
                                         (AS3 u32*)(void*)la1, 16, 0, 0);
        __builtin_amdgcn_global_load_lds((const AS1 u32*)(const void*)(gb0 + k0),
                                         (AS3 u32*)(void*)lb0, 16, 0, 0);
        __builtin_amdgcn_global_load_lds((const AS1 u32*)(const void*)(gb1 + k0),
                                         (AS3 u32*)(void*)lb1, 16, 0, 0);
        __syncthreads();

        bf16x8 af[4], bfr[4];
#pragma unroll
        for (int m = 0; m < 4; m++) af[m] = *(const bf16x8*)(As + afo[m]);
#pragma unroll
        for (int n = 0; n < 4; n++) bfr[n] = *(const bf16x8*)(Bs + bfo[n]);
#pragma unroll
        for (int m = 0; m < 4; m++)
#pragma unroll
            for (int n = 0; n < 4; n++)
                acc[m][n] = __builtin_amdgcn_mfma_f32_16x16x32_bf16(
                    af[m], bfr[n], acc[m][n], 0, 0, 0);
    }

    int rbase = bm * 128 + wr * 64 + lk * 4;
    int cbase = bn * 128 + wc * 64 + lr;
#pragma unroll
    for (int m = 0; m < 4; m++) {
#pragma unroll
        for (int n = 0; n < 4; n++) {
            int c = cbase + n * 16;
            float bb = bias[c];
#pragma unroll
            for (int j = 0; j < 4; j++) {
                int r = rbase + m * 16 + j;
                int orow = (r & 15) * SEQ + (r >> 4);   // [B,S,V] layout
                C[(size_t)orow * N + c] = acc[m][n][j] + bb;
            }
        }
    }
}

// ---------------- persistent LSTM layer: K-split MFMA, reg-direct B ----------
// 256 blocks x 256 threads (4 waves). Block owns 4 hidden units = 16 gate cols.
// Wave w computes K-slice [w*256, w*256+256) via 24 MFMAs (hi*hi + lo*hi + hi*lo);
// B-fragments (h hi/lo) loaded straight from L3 into registers (agent atomics) —
// no LDS h staging. Cross-wave reduce via 4KB LDS partials. G[t+1] prefetched
// during the poll window; Hseq store moved after the arrive store.
__global__ __launch_bounds__(RT) void lstm_layer_persistent(
    const float* __restrict__ Whh,    // [4096][1024] row-major
    const float* __restrict__ G,      // [4096][4096] rows t*16+b (x-proj + biases)
    const float* __restrict__ c_init, // [16][1024]
    float* __restrict__ c_out,        // [16][1024]
    float* __restrict__ Hseq,         // [4096][1024] rows t*16+b
    u16* __restrict__ hx,             // [2 parity][hi 16K | lo 16K] u16, [b][1024]
    u32* __restrict__ arrive,         // [256] monotone epoch slots
    int ebase) {
    __shared__ __align__(16) char lds[69632];
    char* Wlhi = lds;                  // 32 KB, swizzled [c][k]
    char* Wllo = lds + 32768;          // 32 KB
    float* Pw = (float*)(lds + 65536); // [4 wave][64 lane][4] partials (4 KB)

    const int tid = threadIdx.x;
    const int bid = blockIdx.x;
    const int j0 = bid * 4;                  // 4 hidden units per block
    const int w = tid >> 6, l = tid & 63;
    const int ub = l >> 2, ujj = l & 3;      // wave-0 pointwise mapping

    // ---- one-time: stage W_hh slice as bf16 hi/lo into LDS (swizzled) ----
#pragma unroll
    for (int i = 0; i < 8; i++) {
        int q = i * 256 + tid;            // 16B chunk id 0..2047
        int row = q >> 7, cin = q & 127;  // row = gate-col c (0..15)
        int nrow = (row >> 2) * HIDDEN + j0 + (row & 3);
        const float* src = Whh + (size_t)nrow * HIDDEN + cin * 8;
        int dst = row * 2048 + ((cin ^ (row & 7)) << 4);
        u32 hw[4], lw[4];
#pragma unroll
        for (int e = 0; e < 4; e++) {
            float x0 = src[2 * e], x1 = src[2 * e + 1];
            u32 h0 = f2bf(x0), h1 = f2bf(x1);
            hw[e] = h0 | (h1 << 16);
            lw[e] = f2bf(x0 - bf2f(h0)) | (f2bf(x1 - bf2f(h1)) << 16);
        }
        *(uint4*)(Wlhi + dst) = make_uint4(hw[0], hw[1], hw[2], hw[3]);
        *(uint4*)(Wllo + dst) = make_uint4(lw[0], lw[1], lw[2], lw[3]);
    }

    float creg = 0.f;
    float4 g4r = {0.f, 0.f, 0.f, 0.f};
    if (tid < 64) {
        creg = c_init[ub * HIDDEN + j0 + ujj];
        const float* gp = G + ((size_t)(0 * BATCH + ub)) * GATES + j0 + ujj;
        g4r.x = gp[0]; g4r.y = gp[HIDDEN]; g4r.z = gp[2 * HIDDEN]; g4r.w = gp[3 * HIDDEN];
    }
    __syncthreads();   // W staged

    const int row2048 = (l & 15) * 2048;
    const int xr = l & 7;
    const int hi4 = l >> 4;
    const int bidx = (l & 15) * 256 + hi4 * 2;   // u64 index base into h row

    for (int t = 0; t < SEQ; t++) {
        // ---- B-fragment loads: this wave's 8 K-steps, straight from L3 ----
        const u64* hxp = (const u64*)(hx + (t & 1) * 32768);
        u64 bh[16], bl[16];
#pragma unroll
        for (int ss = 0; ss < 8; ss++) {
            int idx = bidx + (w * 8 + ss) * 8;
            bh[2 * ss + 0] = __hip_atomic_load(hxp + idx + 0, __ATOMIC_RELAXED,
                                               __HIP_MEMORY_SCOPE_AGENT);
            bh[2 * ss + 1] = __hip_atomic_load(hxp + idx + 1, __ATOMIC_RELAXED,
                                               __HIP_MEMORY_SCOPE_AGENT);
            bl[2 * ss + 0] = __hip_atomic_load(hxp + 4096 + idx + 0, __ATOMIC_RELAXED,
                                               __HIP_MEMORY_SCOPE_AGENT);
            bl[2 * ss + 1] = __hip_atomic_load(hxp + 4096 + idx + 1, __ATOMIC_RELAXED,
                                               __HIP_MEMORY_SCOPE_AGENT);
        }

        // ---- MFMA over this wave's K-slice: 3 chains (hh, lh, hl) ----
        f32x4 a0 = {0.f,0.f,0.f,0.f}, a1 = {0.f,0.f,0.f,0.f}, a2 = {0.f,0.f,0.f,0.f};
#pragma unroll
        for (int ss = 0; ss < 8; ss++) {
            int s = w * 8 + ss;
            int off = row2048 + ((((s << 2) + hi4) ^ xr) << 4);
            bf16x8 ah = *(const bf16x8*)(Wlhi + off);
            bf16x8 al = *(const bf16x8*)(Wllo + off);
            union { u64 q[2]; bf16x8 v; } ch, cl;
            ch.q[0] = bh[2 * ss + 0]; ch.q[1] = bh[2 * ss + 1];
            cl.q[0] = bl[2 * ss + 0]; cl.q[1] = bl[2 * ss + 1];
            a0 = __builtin_amdgcn_mfma_f32_16x16x32_bf16(ah, ch.v, a0, 0, 0, 0);
            a1 = __builtin_amdgcn_mfma_f32_16x16x32_bf16(al, ch.v, a1, 0, 0, 0);
            a2 = __builtin_amdgcn_mfma_f32_16x16x32_bf16(ah, cl.v, a2, 0, 0, 0);
        }
        f32x4 vs = a0 + a1 + a2;
        *(f32x4*)&Pw[(w * 64 + l) * 4] = vs;
        __syncthreads();

        // ---- wave 0: reduce partials, pointwise, publish, barrier ----
        if (tid < 64) {
            float gs[4];
#pragma unroll
            for (int g = 0; g < 4; g++) {
                int lsrc = (g << 4) | ub;
                gs[g] = Pw[(0 * 64 + lsrc) * 4 + ujj] + Pw[(1 * 64 + lsrc) * 4 + ujj]
                      + Pw[(2 * 64 + lsrc) * 4 + ujj] + Pw[(3 * 64 + lsrc) * 4 + ujj];
            }
            const float ig = 1.f / (1.f + __expf(-(gs[0] + g4r.x)));
            const float fg = 1.f / (1.f + __expf(-(gs[1] + g4r.y)));
            const float gt = tanhf(gs[2] + g4r.z);
            const float og = 1.f / (1.f + __expf(-(gs[3] + g4r.w)));
            creg = fg * creg + ig * gt;
            const float hv = og * tanhf(creg);

            // pack per-batch quads via shuffle; lanes 0-15 publish u64 hi/lo
            float x0 = __shfl(hv, (l & 15) * 4 + 0);
            float x1 = __shfl(hv, (l & 15) * 4 + 1);
            float x2 = __shfl(hv, (l & 15) * 4 + 2);
            float x3 = __shfl(hv, (l & 15) * 4 + 3);
            u32 h0 = f2bf(x0), h1 = f2bf(x1), h2 = f2bf(x2), h3 = f2bf(x3);
            u64 hq = (u64)(h0 | (h1 << 16)) | ((u64)(h2 | (h3 << 16)) << 32);
            u32 l0 = f2bf(x0 - bf2f(h0)), l1 = f2bf(x1 - bf2f(h1));
            u32 l2 = f2bf(x2 - bf2f(h2)), l3 = f2bf(x3 - bf2f(h3));
            u64 lq = (u64)(l0 | (l1 << 16)) | ((u64)(l2 | (l3 << 16)) << 32);
            u16* dhp = hx + ((t & 1) ^ 1) * 32768;
            if (l < 16) {
                __hip_atomic_store((u64*)dhp + ((l * 1024 + j0) >> 2), hq,
                                   __ATOMIC_RELAXED, __HIP_MEMORY_SCOPE_AGENT);
                __hip_atomic_store((u64*)(dhp + 16384) + ((l * 1024 + j0) >> 2), lq,
                                   __ATOMIC_RELAXED, __HIP_MEMORY_SCOPE_AGENT);
            }

            if (t < SEQ - 1) {
                const u32 epoch = (u32)(ebase + t + 1);
                asm volatile("s_waitcnt vmcnt(0)" ::: "memory");  // drain h stores
                if (tid == 0)
                    __hip_atomic_store(&arrive[bid], epoch, __ATOMIC_RELAXED,
                                       __HIP_MEMORY_SCOPE_AGENT);
                // off critical path: G[t+1] prefetch + Hseq[t] store
                {
                    const float* gp = G + ((size_t)((t + 1) * BATCH + ub)) * GATES + j0 + ujj;
                    g4r.x = gp[0]; g4r.y = gp[HIDDEN];
                    g4r.z = gp[2 * HIDDEN]; g4r.w = gp[3 * HIDDEN];
                    Hseq[((size_t)(t * BATCH + ub)) * HIDDEN + j0 + ujj] = hv;
                }
                const int i0 = l * 4;
                for (;;) {
                    u32 a0_ = __hip_atomic_load(&arrive[i0 + 0], __ATOMIC_RELAXED,
                                                __HIP_MEMORY_SCOPE_AGENT);
                    u32 a1_ = __hip_atomic_load(&arrive[i0 + 1], __ATOMIC_RELAXED,
                                                __HIP_MEMORY_SCOPE_AGENT);
                    u32 a2_ = __hip_atomic_load(&arrive[i0 + 2], __ATOMIC_RELAXED,
                                                __HIP_MEMORY_SCOPE_AGENT);
                    u32 a3_ = __hip_atomic_load(&arrive[i0 + 3], __ATOMIC_RELAXED,
                                                __HIP_MEMORY_SCOPE_AGENT);
                    u32 m01 = a0_ < a1_ ? a0_ : a1_;
                    u32 m23 = a2_ < a3_ ? a2_ : a3_;
                    u32 mn = m01 < m23 ? m01 : m23;
                    if (__all(mn >= epoch)) break;
                    __builtin_amdgcn_s_sleep(2);
                }
                asm volatile("" ::: "memory");   // compiler barrier only
            } else {
                Hseq[((size_t)(t * BATCH + ub)) * HIDDEN + j0 + ujj] = hv;
            }
        }
        __syncthreads();   // release all waves into next step
    }
    if (tid < 64) c_out[ub * HIDDEN + j0 + ujj] = creg;
}

// ---------------- init & tails ----------------
__global__ void init_state(const float* __restrict__ h0, const float* __restrict__ c0,
                           float* __restrict__ c_ws, u16* __restrict__ hx,
                           u32* __restrict__ arrive) {
    int gid = blockIdx.x * 256 + threadIdx.x;  // 32768 = 2*16*1024
    if (gid < 256) arrive[gid] = 0;
    c_ws[gid] = c0[gid];
    int layer = gid >> 14, b = (gid >> 10) & 15, j = gid & 1023;
    float h = h0[gid];
    u32 hb = f2bf(h);
    u32 lb = f2bf(h - bf2f(hb));
    u16* base = hx + layer * 65536;          // per-layer region, parity 0
    base[b * 1024 + j] = (u16)hb;
    base[16384 + b * 1024 + j] = (u16)lb;
}

__global__ void write_tails(const float* __restrict__ Hseq0, const float* __restrict__ Hseq1,
                            const float* __restrict__ c_ws, float* __restrict__ out) {
    int gid = blockIdx.x * 256 + threadIdx.x;  // 32768
    int l = gid >> 14, b = (gid >> 10) & 15, j = gid & 1023;
    const float* H = l ? Hseq1 : Hseq0;
    out[LOGITS_SZ + gid] = H[(size_t)((SEQ - 1) * BATCH + b) * HIDDEN + j];
    out[LOGITS_SZ + 32768 + gid] = c_ws[gid];
}

// ---------------- launch ----------------
extern "C" void kernel_launch(void* const* d_in, const int* in_sizes, int n_in,
                              void* d_out, int out_size, void* d_ws, size_t ws_size,
                              hipStream_t stream) {
    const int* x = (const int*)d_in[0];
    const float* h0 = (const float*)d_in[1];
    const float* c0 = (const float*)d_in[2];
    const float* emb = (const float*)d_in[3];
    const float* W_ih0 = (const float*)d_in[4];
    const float* W_hh0 = (const float*)d_in[5];
    const float* b_ih0 = (const float*)d_in[6];
    const float* b_hh0 = (const float*)d_in[7];
    const float* W_ih1 = (const float*)d_in[8];
    const float* W_hh1 = (const float*)d_in[9];
    const float* b_ih1 = (const float*)d_in[10];
    const float* b_hh1 = (const float*)d_in[11];
    const float* fc_W = (const float*)d_in[12];
    const float* fc_b = (const float*)d_in[13];
    float* out = (float*)d_out;
    float* ws = (float*)d_ws;

    // workspace layout (float offsets)
    const size_t OFF_WT0 = 0;                                  // h-exchange (hi/lo, 2 layers)
    const size_t OFF_WT1 = OFF_WT0 + (size_t)GATES * HIDDEN;   // barrier slots
    const size_t OFF_X0 = OFF_WT1 + (size_t)GATES * HIDDEN;    // 4096*512 (reused: Hseq1 bf16)
    const size_t OFF_G = OFF_X0 + (size_t)MROWS * EMBED;       // 4096*4096 (reused: fc_W bf16)
    const size_t OFF_H0S = OFF_G + (size_t)MROWS * GATES;
    const size_t OFF_H1S = OFF_H0S + (size_t)MROWS * HIDDEN;
    const size_t OFF_PARTS = OFF_H1S + (size_t)MROWS * HIDDEN;
    const size_t OFF_C = OFF_PARTS + (size_t)8 * BATCH * GATES;

    u16* hx = (u16*)(ws + OFF_WT0);           // 2 layers x 128 KB
    u32* arrive = (u32*)(ws + OFF_WT1);

    init_state<<<128, 256, 0, stream>>>(h0, c0, ws + OFF_C, hx, arrive);
    embed_kernel<<<MROWS, 128, 0, stream>>>(x, emb, ws + OFF_X0);

    // layer 0: input projection for all timesteps, then persistent recurrence
    gemm_bt<<<dim3(GATES / 128, MROWS / 128), 256, 0, stream>>>(
        ws + OFF_X0, W_ih0, b_ih0, b_hh0, ws + OFF_G, MROWS, GATES, EMBED, 0);
    {
        const float* Gp = ws + OFF_G;
        const float* ci = c0;
        float* co = ws + OFF_C;
        float* hs = ws + OFF_H0S;
        u16* hxl = hx;
        int ebase = 0;
        void* args[] = {(void*)&W_hh0, (void*)&Gp, (void*)&ci, (void*)&co,
                        (void*)&hs, (void*)&hxl, (void*)&arrive, (void*)&ebase};
        hipLaunchCooperativeKernel((void*)lstm_layer_persistent, dim3(RBLOCKS),
                                   dim3(RT), args, 0, stream);
    }

    // layer 1
    gemm_bt<<<dim3(GATES / 128, MROWS / 128), 256, 0, stream>>>(
        ws + OFF_H0S, W_ih1, b_ih1, b_hh1, ws + OFF_G, MROWS, GATES, HIDDEN, 0);
    {
        const float* Gp = ws + OFF_G;
        const float* ci = c0 + BATCH * HIDDEN;
        float* co = ws + OFF_C + BATCH * HIDDEN;
        float* hs = ws + OFF_H1S;
        u16* hxl = hx + 65536;
        int ebase = SEQ;
        void* args[] = {(void*)&W_hh1, (void*)&Gp, (void*)&ci, (void*)&co,
                        (void*)&hs, (void*)&hxl, (void*)&arrive, (void*)&ebase};
        hipLaunchCooperativeKernel((void*)lstm_layer_persistent, dim3(RBLOCKS),
                                   dim3(RT), args, 0, stream);
    }

    // FC via bf16 MFMA: convert operands (G and X0 are dead now), then MFMA GEMM.
    f32_to_bf16_kernel<<<4096, 256, 0, stream>>>(fc_W, (u16*)(ws + OFF_G), VOCAB * HIDDEN / 8);
    f32_to_bf16_kernel<<<2048, 256, 0, stream>>>(ws + OFF_H1S, (u16*)(ws + OFF_X0),
                                                 MROWS * HIDDEN / 8);
    fc_mfma<<<dim3(VOCAB / 128, MROWS / 128), 256, 0, stream>>>(
        (const u16*)(ws + OFF_X0), (const u16*)(ws + OFF_G), fc_b, out);

    write_tails<<<128, 256, 0, stream>>>(ws + OFF_H0S, ws + OFF_H1S, ws + OFF_C, out);
}